// Round 1
// baseline (339.745 us; speedup 1.0000x reference)
//
#include <hip/hip_runtime.h>
#include <hip/hip_bf16.h>
#include <cstdint>
#include <cstddef>

// ---------------------------------------------------------------------------
// QuantizedMultiheadAttention  (N=4, T=2048, E=512, H=8, D=64)
//
// Pipeline:
//  1) proj_quant_kernel x3 : q/k/v = quantize(X @ W^T + b)  [split-bf16 MFMA]
//       q,k -> bf16 [N,H,T,D] ; v -> bf16 [N,H,D,T] (pre-transposed for PV)
//  2) attn_kernel : flash-style online-softmax attention, bf16 MFMA
//       (QK^T exact: quantized values are integers, exact in bf16)
//       ctx -> bf16 [N,T,E]
//  3) outproj_kernel : out = ctx @ Wo^T + bo  (bf16 MFMA, fp32 out)
// ---------------------------------------------------------------------------

typedef __attribute__((ext_vector_type(8))) __bf16 bf16x8;
typedef __attribute__((ext_vector_type(4))) float f32x4;

__device__ __forceinline__ unsigned short f2bf(float x) {
  unsigned u = __float_as_uint(x);
  u += 0x7fffu + ((u >> 16) & 1u);   // round-to-nearest-even
  return (unsigned short)(u >> 16);
}
__device__ __forceinline__ float bf2f(unsigned short h) {
  return __uint_as_float(((unsigned)h) << 16);
}
__device__ __forceinline__ void split2(float x, unsigned short& h, unsigned short& l) {
  unsigned short hb = f2bf(x);
  h = hb;
  l = f2bf(x - bf2f(hb));            // x - bf16(x) is exact in fp32
}

// ---------------------------------------------------------------------------
// Kernel 1: projection + quantize.  C = X[8192,512] @ W^T + bias, quantized.
// Split-bf16: acc = Xh*Wh + Xh*Wl + Xl*Wh  (~2^-17 rel err, avoids floor flips)
// Grid (128 Mtiles, 8 heads), 256 threads (4 waves), 64x64 tile, BK=32.
// transposed==0: dst[((n*8+h)*2048 + t)*64 + d]   (q, k)
// transposed==1: dst[((n*8+h)*64 + d)*2048 + t]   (v, pre-transposed)
// ---------------------------------------------------------------------------
__global__ __launch_bounds__(256) void proj_quant_kernel(
    const float* __restrict__ X, const float* __restrict__ W,
    const float* __restrict__ bias, const float* __restrict__ bparam,
    const float* __restrict__ eparam, unsigned short* __restrict__ dst,
    int transposed)
{
  __shared__ unsigned short sm[4 * 64 * 40];   // Ah | Al | Bh | Bl (20 KB)
  unsigned short* Ah = sm;
  unsigned short* Al = sm + 2560;
  unsigned short* Bh = sm + 5120;
  unsigned short* Bl = sm + 7680;

  const int tid  = threadIdx.x;
  const int wave = tid >> 6;
  const int lane = tid & 63;
  const int quad = lane >> 4;
  const int l16  = lane & 15;
  const int mbase = blockIdx.x * 64;
  const int nbase = blockIdx.y * 64;

  f32x4 acc[4] = {{0.f,0.f,0.f,0.f},{0.f,0.f,0.f,0.f},
                  {0.f,0.f,0.f,0.f},{0.f,0.f,0.f,0.f}};

  const int row0 = tid >> 3;   // 0..31
  const int seg  = tid & 7;    // 0..7 (4 floats each)

  for (int kt = 0; kt < 512; kt += 32) {
#pragma unroll
    for (int half = 0; half < 2; ++half) {
      const int row = row0 + half * 32;
      const float4 xv = *reinterpret_cast<const float4*>(
          X + (size_t)(mbase + row) * 512 + kt + seg * 4);
      const float4 wv = *reinterpret_cast<const float4*>(
          W + (size_t)(nbase + row) * 512 + kt + seg * 4);
      ushort4 xh, xl, wh, wl;
      split2(xv.x, xh.x, xl.x); split2(xv.y, xh.y, xl.y);
      split2(xv.z, xh.z, xl.z); split2(xv.w, xh.w, xl.w);
      split2(wv.x, wh.x, wl.x); split2(wv.y, wh.y, wl.y);
      split2(wv.z, wh.z, wl.z); split2(wv.w, wh.w, wl.w);
      const int off = row * 40 + seg * 4;
      *reinterpret_cast<ushort4*>(&Ah[off]) = xh;
      *reinterpret_cast<ushort4*>(&Al[off]) = xl;
      *reinterpret_cast<ushort4*>(&Bh[off]) = wh;
      *reinterpret_cast<ushort4*>(&Bl[off]) = wl;
    }
    __syncthreads();

    const int ar = (wave * 16 + l16) * 40 + quad * 8;
    const bf16x8 ah = *reinterpret_cast<const bf16x8*>(&Ah[ar]);
    const bf16x8 al = *reinterpret_cast<const bf16x8*>(&Al[ar]);
#pragma unroll
    for (int nf = 0; nf < 4; ++nf) {
      const int br = (nf * 16 + l16) * 40 + quad * 8;
      const bf16x8 bh = *reinterpret_cast<const bf16x8*>(&Bh[br]);
      const bf16x8 bl = *reinterpret_cast<const bf16x8*>(&Bl[br]);
      acc[nf] = __builtin_amdgcn_mfma_f32_16x16x32_bf16(ah, bh, acc[nf], 0, 0, 0);
      acc[nf] = __builtin_amdgcn_mfma_f32_16x16x32_bf16(ah, bl, acc[nf], 0, 0, 0);
      acc[nf] = __builtin_amdgcn_mfma_f32_16x16x32_bf16(al, bh, acc[nf], 0, 0, 0);
    }
    __syncthreads();
  }

  // quantize: floor(clip(x/2^e, -2^(b-1), 2^(b-1)-1)) * 2^e,  b=clip(b,1,8)
  const float bq   = fminf(fmaxf(bparam[0], 1.0f), 8.0f);
  const float e    = eparam[0];
  const float s    = exp2f(e);
  const float invs = exp2f(-e);
  const float qlo  = -exp2f(bq - 1.0f);
  const float qhi  = exp2f(bq - 1.0f) - 1.0f;

  // stage quantized tile in LDS [64][72] for coalesced global stores
#pragma unroll
  for (int nf = 0; nf < 4; ++nf) {
    const float bv = bias[nbase + nf * 16 + l16];
#pragma unroll
    for (int reg = 0; reg < 4; ++reg) {
      const float v  = acc[nf][reg] + bv;
      const float qv = floorf(fminf(fmaxf(v * invs, qlo), qhi)) * s;
      const int ml = wave * 16 + quad * 4 + reg;   // C row = quad*4+reg
      const int nl = nf * 16 + l16;                // C col = lane&15
      const int r = transposed ? nl : ml;
      const int c = transposed ? ml : nl;
      sm[r * 72 + c] = f2bf(qv);
    }
  }
  __syncthreads();

  const int nidx = mbase >> 11;     // batch index
  const int tb   = mbase & 2047;    // t base
  const int h    = blockIdx.y;
  const int rr   = tid >> 2;
  const int c16  = (tid & 3) * 16;
  const uint4 v0 = *reinterpret_cast<const uint4*>(&sm[rr * 72 + c16]);
  const uint4 v1 = *reinterpret_cast<const uint4*>(&sm[rr * 72 + c16 + 8]);
  size_t o;
  if (!transposed) o = ((size_t)((nidx * 8 + h) * 2048 + tb + rr)) * 64 + c16;
  else             o = ((size_t)((nidx * 8 + h) * 64 + rr)) * 2048 + tb + c16;
  *reinterpret_cast<uint4*>(&dst[o])     = v0;
  *reinterpret_cast<uint4*>(&dst[o + 8]) = v1;
}

// ---------------------------------------------------------------------------
// Kernel 2: flash attention. Grid (32 qtiles, 8 heads, 4 batch), 256 threads.
// Per block: 64 q rows; wave w owns rows w*16..w*16+15. K-loop over 32 tiles
// of 64 keys. energy/sqrt(512); softmax in exp2 domain.
// ---------------------------------------------------------------------------
__global__ __launch_bounds__(256) void attn_kernel(
    const unsigned short* __restrict__ qbuf,
    const unsigned short* __restrict__ kbuf,
    const unsigned short* __restrict__ vtbuf,
    unsigned short* __restrict__ ctx)
{
  __shared__ unsigned short Kt[64 * 72];   // [key][d]
  __shared__ unsigned short Vt[64 * 72];   // [d][key]
  __shared__ unsigned short Pl[64 * 72];   // per-wave P rows; epilogue tile

  const int tid  = threadIdx.x;
  const int wave = tid >> 6;
  const int lane = tid & 63;
  const int quad = lane >> 4;
  const int l16  = lane & 15;
  const int qt = blockIdx.x, h = blockIdx.y, n = blockIdx.z;
  const int nh = n * 8 + h;

  const unsigned short* Qp = qbuf + ((size_t)nh * 2048 + qt * 64) * 64;
  const unsigned short* Kp = kbuf + (size_t)nh * 2048 * 64;
  const unsigned short* Vp = vtbuf + (size_t)nh * 64 * 2048;

  // Q A-fragments held in registers for the whole kernel (exact bf16 ints)
  const int qrow = wave * 16 + l16;
  const bf16x8 qf0 = *reinterpret_cast<const bf16x8*>(Qp + qrow * 64 + quad * 8);
  const bf16x8 qf1 = *reinterpret_cast<const bf16x8*>(Qp + qrow * 64 + 32 + quad * 8);

  const float sc = 0.044194173824159216f * 1.4426950408889634f; // 1/sqrt(512)*log2(e)

  float m_r[4], l_r[4];
#pragma unroll
  for (int i = 0; i < 4; ++i) { m_r[i] = -INFINITY; l_r[i] = 0.f; }
  f32x4 O[4] = {{0.f,0.f,0.f,0.f},{0.f,0.f,0.f,0.f},
                {0.f,0.f,0.f,0.f},{0.f,0.f,0.f,0.f}};

  const int srow = tid >> 2;           // 0..63
  const int sseg = (tid & 3) * 16;     // 16-elem segment

  for (int kt = 0; kt < 2048; kt += 64) {
    { // stage K tile [64 keys][64 d] and V^T tile [64 d][64 keys]
      const unsigned short* gk = Kp + (size_t)(kt + srow) * 64 + sseg;
      *reinterpret_cast<uint4*>(&Kt[srow * 72 + sseg])     = *reinterpret_cast<const uint4*>(gk);
      *reinterpret_cast<uint4*>(&Kt[srow * 72 + sseg + 8]) = *reinterpret_cast<const uint4*>(gk + 8);
      const unsigned short* gv = Vp + (size_t)srow * 2048 + kt + sseg;
      *reinterpret_cast<uint4*>(&Vt[srow * 72 + sseg])     = *reinterpret_cast<const uint4*>(gv);
      *reinterpret_cast<uint4*>(&Vt[srow * 72 + sseg + 8]) = *reinterpret_cast<const uint4*>(gv + 8);
    }
    __syncthreads();

    // S = Q K^T   (exact: integer inputs)
    f32x4 sf[4];
#pragma unroll
    for (int kf = 0; kf < 4; ++kf) {
      const int kr = (kf * 16 + l16) * 72 + quad * 8;
      const bf16x8 kb0 = *reinterpret_cast<const bf16x8*>(&Kt[kr]);
      const bf16x8 kb1 = *reinterpret_cast<const bf16x8*>(&Kt[kr + 32]);
      f32x4 z = {0.f, 0.f, 0.f, 0.f};
      z = __builtin_amdgcn_mfma_f32_16x16x32_bf16(qf0, kb0, z, 0, 0, 0);
      z = __builtin_amdgcn_mfma_f32_16x16x32_bf16(qf1, kb1, z, 0, 0, 0);
      sf[kf] = z;
    }

    // online softmax; C-layout row = quad*4+reg, 16 lanes/row share quad
#pragma unroll
    for (int reg = 0; reg < 4; ++reg) {
      float s0 = sf[0][reg] * sc, s1 = sf[1][reg] * sc;
      float s2 = sf[2][reg] * sc, s3 = sf[3][reg] * sc;
      float mx = fmaxf(fmaxf(s0, s1), fmaxf(s2, s3));
#pragma unroll
      for (int d = 1; d < 16; d <<= 1) mx = fmaxf(mx, __shfl_xor(mx, d));
      const float mn = fmaxf(m_r[reg], mx);
      const float alpha = exp2f(m_r[reg] - mn);
      m_r[reg] = mn;
      const float p0 = exp2f(s0 - mn), p1 = exp2f(s1 - mn);
      const float p2 = exp2f(s2 - mn), p3 = exp2f(s3 - mn);
      float rs = (p0 + p1) + (p2 + p3);
#pragma unroll
      for (int d = 1; d < 16; d <<= 1) rs += __shfl_xor(rs, d);
      l_r[reg] = l_r[reg] * alpha + rs;
#pragma unroll
      for (int df = 0; df < 4; ++df) O[df][reg] *= alpha;
      // P to LDS (C-layout -> A-layout round trip), per-wave region
      const int pr = (wave * 16 + quad * 4 + reg) * 72 + l16;
      Pl[pr]      = f2bf(p0);
      Pl[pr + 16] = f2bf(p1);
      Pl[pr + 32] = f2bf(p2);
      Pl[pr + 48] = f2bf(p3);
    }

    // O += P @ V
    const int par = (wave * 16 + l16) * 72 + quad * 8;
    const bf16x8 a0 = *reinterpret_cast<const bf16x8*>(&Pl[par]);
    const bf16x8 a1 = *reinterpret_cast<const bf16x8*>(&Pl[par + 32]);
#pragma unroll
    for (int df = 0; df < 4; ++df) {
      const int vr = (df * 16 + l16) * 72 + quad * 8;
      const bf16x8 vb0 = *reinterpret_cast<const bf16x8*>(&Vt[vr]);
      const bf16x8 vb1 = *reinterpret_cast<const bf16x8*>(&Vt[vr + 32]);
      O[df] = __builtin_amdgcn_mfma_f32_16x16x32_bf16(a0, vb0, O[df], 0, 0, 0);
      O[df] = __builtin_amdgcn_mfma_f32_16x16x32_bf16(a1, vb1, O[df], 0, 0, 0);
    }
    __syncthreads();
  }

  // epilogue: normalize, merge heads -> ctx [N,T,E] bf16 (LDS-staged stores)
#pragma unroll
  for (int df = 0; df < 4; ++df) {
#pragma unroll
    for (int reg = 0; reg < 4; ++reg) {
      const float v = O[df][reg] / l_r[reg];
      Pl[(wave * 16 + quad * 4 + reg) * 72 + df * 16 + l16] = f2bf(v);
    }
  }
  __syncthreads();
  const int rr  = tid >> 2;
  const int c16 = (tid & 3) * 16;
  const uint4 v0 = *reinterpret_cast<const uint4*>(&Pl[rr * 72 + c16]);
  const uint4 v1 = *reinterpret_cast<const uint4*>(&Pl[rr * 72 + c16 + 8]);
  const size_t o = ((size_t)n * 2048 + qt * 64 + rr) * 512 + h * 64 + c16;
  *reinterpret_cast<uint4*>(&ctx[o])     = v0;
  *reinterpret_cast<uint4*>(&ctx[o + 8]) = v1;
}

// ---------------------------------------------------------------------------
// Kernel 3: out = ctx @ Wo^T + bo   (bf16 MFMA, fp32 output)
// ---------------------------------------------------------------------------
__global__ __launch_bounds__(256) void outproj_kernel(
    const unsigned short* __restrict__ ctx, const float* __restrict__ W,
    const float* __restrict__ bias, float* __restrict__ out)
{
  __shared__ unsigned short sA[64 * 40];
  __shared__ unsigned short sB[64 * 40];
  const int tid  = threadIdx.x;
  const int wave = tid >> 6;
  const int lane = tid & 63;
  const int quad = lane >> 4;
  const int l16  = lane & 15;
  const int mbase = blockIdx.x * 64, nbase = blockIdx.y * 64;

  f32x4 acc[4] = {{0.f,0.f,0.f,0.f},{0.f,0.f,0.f,0.f},
                  {0.f,0.f,0.f,0.f},{0.f,0.f,0.f,0.f}};
  const int row = tid >> 2, seg = tid & 3;

  for (int kt = 0; kt < 512; kt += 32) {
    *reinterpret_cast<uint4*>(&sA[row * 40 + seg * 8]) =
        *reinterpret_cast<const uint4*>(&ctx[(size_t)(mbase + row) * 512 + kt + seg * 8]);
    const float* wp = W + (size_t)(nbase + row) * 512 + kt + seg * 8;
    const float4 w0 = *reinterpret_cast<const float4*>(wp);
    const float4 w1 = *reinterpret_cast<const float4*>(wp + 4);
    const ushort4 b0 = {f2bf(w0.x), f2bf(w0.y), f2bf(w0.z), f2bf(w0.w)};
    const ushort4 b1 = {f2bf(w1.x), f2bf(w1.y), f2bf(w1.z), f2bf(w1.w)};
    *reinterpret_cast<ushort4*>(&sB[row * 40 + seg * 8])     = b0;
    *reinterpret_cast<ushort4*>(&sB[row * 40 + seg * 8 + 4]) = b1;
    __syncthreads();

    const bf16x8 a = *reinterpret_cast<const bf16x8*>(&sA[(wave * 16 + l16) * 40 + quad * 8]);
#pragma unroll
    for (int nf = 0; nf < 4; ++nf) {
      const bf16x8 b = *reinterpret_cast<const bf16x8*>(&sB[(nf * 16 + l16) * 40 + quad * 8]);
      acc[nf] = __builtin_amdgcn_mfma_f32_16x16x32_bf16(a, b, acc[nf], 0, 0, 0);
    }
    __syncthreads();
  }

#pragma unroll
  for (int nf = 0; nf < 4; ++nf) {
    const float bv = bias[nbase + nf * 16 + l16];
#pragma unroll
    for (int reg = 0; reg < 4; ++reg) {
      const int r = mbase + wave * 16 + quad * 4 + reg;
      const int c = nbase + nf * 16 + l16;
      out[(size_t)r * 512 + c] = acc[nf][reg] + bv;
    }
  }
}

// ---------------------------------------------------------------------------
extern "C" void kernel_launch(void* const* d_in, const int* in_sizes, int n_in,
                              void* d_out, int out_size, void* d_ws, size_t ws_size,
                              hipStream_t stream) {
  const float* values = (const float*)d_in[0];
  const float* keys   = (const float*)d_in[1];
  const float* query  = (const float*)d_in[2];
  const float* Wq = (const float*)d_in[3];
  const float* bq = (const float*)d_in[4];
  const float* Wk = (const float*)d_in[5];
  const float* bk = (const float*)d_in[6];
  const float* Wv = (const float*)d_in[7];
  const float* bv = (const float*)d_in[8];
  const float* Wo = (const float*)d_in[9];
  const float* bo = (const float*)d_in[10];
  const float* bp = (const float*)d_in[11];
  const float* ep = (const float*)d_in[12];

  const size_t NHTD = (size_t)4 * 8 * 2048 * 64;   // 4,194,304 elems
  unsigned short* qbuf  = (unsigned short*)d_ws;
  unsigned short* kbuf  = qbuf + NHTD;
  unsigned short* vtbuf = kbuf + NHTD;
  unsigned short* ctx   = vtbuf + NHTD;            // total 32 MB of ws

  dim3 pg(128, 8), pb(256);
  proj_quant_kernel<<<pg, pb, 0, stream>>>(query,  Wq, bq, bp, ep, qbuf,  0);
  proj_quant_kernel<<<pg, pb, 0, stream>>>(keys,   Wk, bk, bp, ep, kbuf,  0);
  proj_quant_kernel<<<pg, pb, 0, stream>>>(values, Wv, bv, bp, ep, vtbuf, 1);
  attn_kernel<<<dim3(32, 8, 4), 256, 0, stream>>>(qbuf, kbuf, vtbuf, ctx);
  outproj_kernel<<<dim3(128, 8), 256, 0, stream>>>(ctx, Wo, bo, (float*)d_out);
}

// Round 2
// 320.549 us; speedup vs baseline: 1.0599x; 1.0599x over previous
//
#include <hip/hip_runtime.h>
#include <hip/hip_bf16.h>
#include <cstdint>
#include <cstddef>

// ---------------------------------------------------------------------------
// QuantizedMultiheadAttention  (N=4, T=2048, E=512, H=8, D=64)
//
//  prep_w / prep_split : fp32 -> split-bf16 (h + l) buffers, computed ONCE
//  proj_kernel  : q/k/v = quantize(X@W^T+b), 3-pass split-bf16 MFMA 32x32x16,
//                 128x128 tiles, global_load_lds(16B), XOR-swizzled LDS.
//                 v stored pre-transposed [N,H,D,T].
//  attn_kernel  : barrier-free flash attention; S^T trick (A=K,B=Q) puts each
//                 Q-row's scores in one lane -> no-max softmax = per-lane adds.
//                 K/V fragments read direct from global (L1/L2), P transform
//                 through wave-private swizzled LDS.
//  outproj      : out = ctx@Wo^T + bo (bf16 MFMA, fp32 out)
// ---------------------------------------------------------------------------

typedef __attribute__((ext_vector_type(8))) __bf16 bf16x8;
typedef __attribute__((ext_vector_type(16))) float f32x16;
typedef unsigned short u16;

#define EL  4194304   // 4*2048*512 elements (one X-like matrix / qkv buf)
#define WEL 262144    // 512*512

static __device__ __forceinline__ u16 f2bf(float x) {
  unsigned u = __float_as_uint(x);
  u += 0x7fffu + ((u >> 16) & 1u);           // round-to-nearest-even
  return (u16)(u >> 16);
}
static __device__ __forceinline__ float bf2f(u16 h) {
  return __uint_as_float(((unsigned)h) << 16);
}
static __device__ __forceinline__ void split2(float x, u16& h, u16& l) {
  u16 hb = f2bf(x); h = hb; l = f2bf(x - bf2f(hb));   // residual exact in fp32
}
static __device__ __forceinline__ unsigned pk2(float a, float b) {
  return (unsigned)f2bf(a) | ((unsigned)f2bf(b) << 16);
}
static __device__ __forceinline__ void gl_lds16(const void* g, void* l) {
  __builtin_amdgcn_global_load_lds(
      (__attribute__((address_space(1))) void*)g,
      (__attribute__((address_space(3))) void*)l, 16, 0, 0);
}

// ---------------------------------------------------------------------------
// prep kernels: one-time fp32 -> bf16 split conversions
// ---------------------------------------------------------------------------
__global__ __launch_bounds__(256) void prep_split_kernel(
    const float* __restrict__ src, u16* __restrict__ dh, u16* __restrict__ dl,
    int n4)
{
  int i = blockIdx.x * 256 + threadIdx.x;
  if (i >= n4) return;
  float4 v = ((const float4*)src)[i];
  ushort4 h, l;
  split2(v.x, h.x, l.x); split2(v.y, h.y, l.y);
  split2(v.z, h.z, l.z); split2(v.w, h.w, l.w);
  ((ushort4*)dh)[i] = h; ((ushort4*)dl)[i] = l;
}

__global__ __launch_bounds__(256) void prep_w_kernel(
    const float* __restrict__ Wq, const float* __restrict__ Wk,
    const float* __restrict__ Wv, const float* __restrict__ Wo,
    u16* __restrict__ wb)
{
  const int y = blockIdx.y;
  const float* src = (y == 0) ? Wq : (y == 1) ? Wk : (y == 2) ? Wv : Wo;
  int i = blockIdx.x * 256 + threadIdx.x;     // 65536 threads = WEL/4
  float4 v = ((const float4*)src)[i];
  if (y < 3) {
    ushort4 h, l;
    split2(v.x, h.x, l.x); split2(v.y, h.y, l.y);
    split2(v.z, h.z, l.z); split2(v.w, h.w, l.w);
    ((ushort4*)(wb + (size_t)y * 2 * WEL))[i] = h;
    ((ushort4*)(wb + (size_t)y * 2 * WEL + WEL))[i] = l;
  } else {
    ushort4 h;
    h.x = f2bf(v.x); h.y = f2bf(v.y); h.z = f2bf(v.z); h.w = f2bf(v.w);
    ((ushort4*)(wb + (size_t)6 * WEL))[i] = h;
  }
}

// ---------------------------------------------------------------------------
// proj: C = quantize(X@W^T + b), 3-pass split-bf16, 128x128 tile, BK=32
// ---------------------------------------------------------------------------
struct ProjArgs {
  const u16* Xh[3]; const u16* Xl[3];
  const u16* Wh[3]; const u16* Wl[3];
  const float* bias[3];
  u16* dst[3];
  int trans[3];
};

__global__ __launch_bounds__(256) void proj_kernel(ProjArgs args,
    const float* __restrict__ bparam, const float* __restrict__ eparam)
{
  __shared__ u16 sm[17408];                 // 34.8 KB (staging 32 KB + T-epilogue)
  u16* const Ah = sm;
  u16* const Al = sm + 4096;
  u16* const Bh = sm + 8192;
  u16* const Bl = sm + 12288;

  const int z = blockIdx.z;
  const u16* __restrict__ Xh = args.Xh[z];
  const u16* __restrict__ Xl = args.Xl[z];
  const u16* __restrict__ Wh = args.Wh[z];
  const u16* __restrict__ Wl = args.Wl[z];
  const float* __restrict__ bias = args.bias[z];
  u16* __restrict__ dst = args.dst[z];
  const int trans = args.trans[z];

  const int tid  = threadIdx.x;
  const int lane = tid & 63;
  const int wave = tid >> 6;
  const int lam  = lane & 31;
  const int hl   = lane >> 5;
  const int wm   = wave & 1;
  const int wn   = wave >> 1;
  const int mbase = blockIdx.x * 128;
  const int nbase = blockIdx.y * 128;

  // staging: chunk c=tid and c=tid+256 per tile; row=c>>2, kc=((c&3)-(c>>4))&3
  const int srow = tid >> 2;
  const int skc  = ((tid & 3) - (tid >> 4)) & 3;
  const u16* gAh = Xh + (size_t)(mbase + srow) * 512 + skc * 8;
  const u16* gAl = Xl + (size_t)(mbase + srow) * 512 + skc * 8;
  const u16* gBh = Wh + (size_t)(nbase + srow) * 512 + skc * 8;
  const u16* gBl = Wl + (size_t)(nbase + srow) * 512 + skc * 8;
  const int lo = tid * 8;                   // chunk byte/2 offset in each tile

  // fragment LDS byte offsets (XOR-swizzled: pos = (kchunk + (row>>2)) & 3)
  int offA[2][2], offB[2][2];
#pragma unroll
  for (int f = 0; f < 2; ++f)
#pragma unroll
    for (int kk = 0; kk < 2; ++kk) {
      int m = wm * 64 + f * 32 + lam;
      offA[f][kk] = m * 64 + (((2 * kk + hl) + (m >> 2)) & 3) * 16;
      int nn = wn * 64 + f * 32 + lam;
      offB[f][kk] = nn * 64 + (((2 * kk + hl) + (nn >> 2)) & 3) * 16;
    }

  f32x16 acc[2][2];
#pragma unroll
  for (int a = 0; a < 2; ++a)
#pragma unroll
    for (int b = 0; b < 2; ++b)
#pragma unroll
      for (int i = 0; i < 16; ++i) acc[a][b][i] = 0.f;

  for (int kt = 0; kt < 512; kt += 32) {
    __syncthreads();                        // prior frag reads done
    gl_lds16(gAh + kt,             Ah + lo);
    gl_lds16(gAh + kt + 64 * 512,  Ah + lo + 2048);
    gl_lds16(gAl + kt,             Al + lo);
    gl_lds16(gAl + kt + 64 * 512,  Al + lo + 2048);
    gl_lds16(gBh + kt,             Bh + lo);
    gl_lds16(gBh + kt + 64 * 512,  Bh + lo + 2048);
    gl_lds16(gBl + kt,             Bl + lo);
    gl_lds16(gBl + kt + 64 * 512,  Bl + lo + 2048);
    __syncthreads();                        // vmcnt(0) drained before barrier

    bf16x8 fAh[2][2], fAl[2][2], fBh[2][2], fBl[2][2];
#pragma unroll
    for (int f = 0; f < 2; ++f)
#pragma unroll
      for (int kk = 0; kk < 2; ++kk) {
        fAh[f][kk] = *(const bf16x8*)((const char*)Ah + offA[f][kk]);
        fAl[f][kk] = *(const bf16x8*)((const char*)Al + offA[f][kk]);
        fBh[f][kk] = *(const bf16x8*)((const char*)Bh + offB[f][kk]);
        fBl[f][kk] = *(const bf16x8*)((const char*)Bl + offB[f][kk]);
      }
#pragma unroll
    for (int mf = 0; mf < 2; ++mf)
#pragma unroll
      for (int nf = 0; nf < 2; ++nf)
#pragma unroll
        for (int kk = 0; kk < 2; ++kk) {
          acc[mf][nf] = __builtin_amdgcn_mfma_f32_32x32x16_bf16(
              fAh[mf][kk], fBh[nf][kk], acc[mf][nf], 0, 0, 0);
          acc[mf][nf] = __builtin_amdgcn_mfma_f32_32x32x16_bf16(
              fAh[mf][kk], fBl[nf][kk], acc[mf][nf], 0, 0, 0);
          acc[mf][nf] = __builtin_amdgcn_mfma_f32_32x32x16_bf16(
              fAl[mf][kk], fBh[nf][kk], acc[mf][nf], 0, 0, 0);
        }
  }

  // quantize epilogue
  const float bq   = fminf(fmaxf(bparam[0], 1.0f), 8.0f);
  const float e    = eparam[0];
  const float s    = exp2f(e);
  const float invs = exp2f(-e);
  const float qlo  = -exp2f(bq - 1.0f);
  const float qhi  = exp2f(bq - 1.0f) - 1.0f;
  const int nidx = mbase >> 11;             // batch
  const int tb   = mbase & 2047;            // t base
  const int hb   = nbase >> 6;              // head base (2 heads per col-tile)

  if (!trans) {
#pragma unroll
    for (int mf = 0; mf < 2; ++mf)
#pragma unroll
      for (int nf = 0; nf < 2; ++nf)
#pragma unroll
        for (int reg = 0; reg < 16; ++reg) {
          int col = wn * 64 + nf * 32 + lam;
          int row = wm * 64 + mf * 32 + (reg & 3) + 8 * (reg >> 2) + 4 * hl;
          float v = acc[mf][nf][reg] + bias[nbase + col];
          float qv = floorf(fminf(fmaxf(v * invs, qlo), qhi)) * s;
          dst[((size_t)(nidx * 8 + hb + (col >> 6)) * 2048 + tb + row) * 64 +
              (col & 63)] = f2bf(qv);
        }
  } else {
    __syncthreads();                        // staging LDS reads done everywhere
#pragma unroll
    for (int mf = 0; mf < 2; ++mf)
#pragma unroll
      for (int nf = 0; nf < 2; ++nf)
#pragma unroll
        for (int reg = 0; reg < 16; ++reg) {
          int col = wn * 64 + nf * 32 + lam;
          int row = wm * 64 + mf * 32 + (reg & 3) + 8 * (reg >> 2) + 4 * hl;
          float v = acc[mf][nf][reg] + bias[nbase + col];
          float qv = floorf(fminf(fmaxf(v * invs, qlo), qhi)) * s;
          sm[col * 136 + row] = f2bf(qv);   // [d-ish col][t row], stride 136
        }
    __syncthreads();
    const int r = tid >> 1, half = tid & 1;
    const u16* sp = sm + r * 136 + half * 64;
    u16* gp = dst + ((size_t)(nidx * 8 + hb + (r >> 6)) * 64 + (r & 63)) * 2048 +
              tb + half * 64;
#pragma unroll
    for (int i = 0; i < 8; ++i)
      *(uint4*)(gp + i * 8) = *(const uint4*)(sp + i * 8);
  }
}

// ---------------------------------------------------------------------------
// attn: barrier-free flash attention, 128 q-rows/block (32 per wave)
// ---------------------------------------------------------------------------
__global__ __launch_bounds__(256) void attn_kernel(
    const u16* __restrict__ qbuf, const u16* __restrict__ kbuf,
    const u16* __restrict__ vtbuf, u16* __restrict__ ctx)
{
  __shared__ u16 P[8192];                   // 16 KB, 4 KB per wave (private)
  const int tid  = threadIdx.x;
  const int wave = tid >> 6;
  const int lane = tid & 63;
  const int lam  = lane & 31;
  const int hl   = lane >> 5;
  const int qt = blockIdx.x, hd = blockIdx.y, n = blockIdx.z;
  const int nh = n * 8 + hd;
  const int qbase = qt * 128 + wave * 32;

  const u16* Qp = qbuf + ((size_t)nh * 2048 + qbase) * 64;
  const u16* Kp = kbuf + (size_t)nh * 131072;
  const u16* Vp = vtbuf + (size_t)nh * 131072;

  bf16x8 qf[4];                             // B-operand: B[n=lam][k=dk*16+hl*8+j]
#pragma unroll
  for (int dk = 0; dk < 4; ++dk)
    qf[dk] = *(const bf16x8*)(Qp + lam * 64 + dk * 16 + hl * 8);

  const float sc = (float)(1.4426950408889634 / 22.627416997969522); // log2e/sqrt(512)

  char* const Pwb = (char*)(P + wave * 2048);
  int pwoff[2][4], proff[4];
#pragma unroll
  for (int kf = 0; kf < 2; ++kf)
#pragma unroll
    for (int r4 = 0; r4 < 4; ++r4)
      pwoff[kf][r4] = lam * 128 + ((kf * 4 + r4 + lam) & 7) * 16 + hl * 8;
#pragma unroll
  for (int kk = 0; kk < 4; ++kk)
    proff[kk] = lam * 128 + ((2 * kk + hl + lam) & 7) * 16;

  float l_acc = 0.f;
  f32x16 O[2];
#pragma unroll
  for (int a = 0; a < 2; ++a)
#pragma unroll
    for (int i = 0; i < 16; ++i) O[a][i] = 0.f;

  for (int kt = 0; kt < 2048; kt += 64) {
    // S^T = K Q^T   (A = K rows, B = Q rows; exact: integer-valued inputs)
#pragma unroll
    for (int kf = 0; kf < 2; ++kf) {
      f32x16 S;
#pragma unroll
      for (int i = 0; i < 16; ++i) S[i] = 0.f;
      const u16* Kr = Kp + (size_t)(kt + kf * 32 + lam) * 64 + hl * 8;
#pragma unroll
      for (int dk = 0; dk < 4; ++dk)
        S = __builtin_amdgcn_mfma_f32_32x32x16_bf16(
            *(const bf16x8*)(Kr + dk * 16), qf[dk], S, 0, 0, 0);
      // no-max softmax partials: all 16 scores belong to q-row lam
#pragma unroll
      for (int r4 = 0; r4 < 4; ++r4) {
        float p0 = __builtin_amdgcn_exp2f(S[r4 * 4 + 0] * sc);
        float p1 = __builtin_amdgcn_exp2f(S[r4 * 4 + 1] * sc);
        float p2 = __builtin_amdgcn_exp2f(S[r4 * 4 + 2] * sc);
        float p3 = __builtin_amdgcn_exp2f(S[r4 * 4 + 3] * sc);
        l_acc += (p0 + p1) + (p2 + p3);
        uint2 u; u.x = pk2(p0, p1); u.y = pk2(p2, p3);
        *(uint2*)(Pwb + pwoff[kf][r4]) = u;  // P[qrow=lam][4 consecutive keys]
      }
    }
    // O += P V   (A = P rows from LDS, B = V^T rows direct from global)
    bf16x8 pa[4];
#pragma unroll
    for (int kk = 0; kk < 4; ++kk)
      pa[kk] = *(const bf16x8*)(Pwb + proff[kk]);
#pragma unroll
    for (int nf = 0; nf < 2; ++nf) {
      const u16* Vr = Vp + (size_t)(nf * 32 + lam) * 2048 + kt + hl * 8;
#pragma unroll
      for (int kk = 0; kk < 4; ++kk)
        O[nf] = __builtin_amdgcn_mfma_f32_32x32x16_bf16(
            pa[kk], *(const bf16x8*)(Vr + kk * 16), O[nf], 0, 0, 0);
    }
  }

  // epilogue: one cross-lane combine, normalize, store ctx [N,T,E]
  l_acc += __shfl_xor(l_acc, 32);
  const float rinv = 1.0f / l_acc;          // lane holds 1/l[qrow=lam]
  float rv[16];
#pragma unroll
  for (int reg = 0; reg < 16; ++reg)
    rv[reg] = __shfl(rinv, (reg & 3) + 8 * (reg >> 2) + 4 * hl);
#pragma unroll
  for (int nf = 0; nf < 2; ++nf)
#pragma unroll
    for (int reg = 0; reg < 16; ++reg) {
      int row = (reg & 3) + 8 * (reg >> 2) + 4 * hl;
      float v = O[nf][reg] * rv[reg];
      ctx[((size_t)n * 2048 + qbase + row) * 512 + hd * 64 + nf * 32 + lam] =
          f2bf(v);
    }
}

// ---------------------------------------------------------------------------
// outproj: out = ctx @ Wo^T + bo  (single-pass bf16, fp32 out)
// ---------------------------------------------------------------------------
__global__ __launch_bounds__(256) void outproj_kernel(
    const u16* __restrict__ ctxb, const u16* __restrict__ Wob,
    const float* __restrict__ bias, float* __restrict__ out)
{
  __shared__ u16 sm[8192];
  u16* const As = sm;
  u16* const Bs = sm + 4096;

  const int tid  = threadIdx.x;
  const int lane = tid & 63;
  const int wave = tid >> 6;
  const int lam  = lane & 31;
  const int hl   = lane >> 5;
  const int wm   = wave & 1;
  const int wn   = wave >> 1;
  const int mbase = blockIdx.x * 128;
  const int nbase = blockIdx.y * 128;

  const int srow = tid >> 2;
  const int skc  = ((tid & 3) - (tid >> 4)) & 3;
  const u16* gA = ctxb + (size_t)(mbase + srow) * 512 + skc * 8;
  const u16* gB = Wob  + (size_t)(nbase + srow) * 512 + skc * 8;
  const int lo = tid * 8;

  int offA[2][2], offB[2][2];
#pragma unroll
  for (int f = 0; f < 2; ++f)
#pragma unroll
    for (int kk = 0; kk < 2; ++kk) {
      int m = wm * 64 + f * 32 + lam;
      offA[f][kk] = m * 64 + (((2 * kk + hl) + (m >> 2)) & 3) * 16;
      int nn = wn * 64 + f * 32 + lam;
      offB[f][kk] = nn * 64 + (((2 * kk + hl) + (nn >> 2)) & 3) * 16;
    }

  f32x16 acc[2][2];
#pragma unroll
  for (int a = 0; a < 2; ++a)
#pragma unroll
    for (int b = 0; b < 2; ++b)
#pragma unroll
      for (int i = 0; i < 16; ++i) acc[a][b][i] = 0.f;

  for (int kt = 0; kt < 512; kt += 32) {
    __syncthreads();
    gl_lds16(gA + kt,            As + lo);
    gl_lds16(gA + kt + 64 * 512, As + lo + 2048);
    gl_lds16(gB + kt,            Bs + lo);
    gl_lds16(gB + kt + 64 * 512, Bs + lo + 2048);
    __syncthreads();

    bf16x8 fA[2][2], fB[2][2];
#pragma unroll
    for (int f = 0; f < 2; ++f)
#pragma unroll
      for (int kk = 0; kk < 2; ++kk) {
        fA[f][kk] = *(const bf16x8*)((const char*)As + offA[f][kk]);
        fB[f][kk] = *(const bf16x8*)((const char*)Bs + offB[f][kk]);
      }
#pragma unroll
    for (int mf = 0; mf < 2; ++mf)
#pragma unroll
      for (int nf = 0; nf < 2; ++nf)
#pragma unroll
        for (int kk = 0; kk < 2; ++kk)
          acc[mf][nf] = __builtin_amdgcn_mfma_f32_32x32x16_bf16(
              fA[mf][kk], fB[nf][kk], acc[mf][nf], 0, 0, 0);
  }

#pragma unroll
  for (int mf = 0; mf < 2; ++mf)
#pragma unroll
    for (int nf = 0; nf < 2; ++nf)
#pragma unroll
      for (int reg = 0; reg < 16; ++reg) {
        int col = wn * 64 + nf * 32 + lam;
        int row = wm * 64 + mf * 32 + (reg & 3) + 8 * (reg >> 2) + 4 * hl;
        out[(size_t)(mbase + row) * 512 + nbase + col] =
            acc[mf][nf][reg] + bias[nbase + col];
      }
}

// ---------------------------------------------------------------------------
extern "C" void kernel_launch(void* const* d_in, const int* in_sizes, int n_in,
                              void* d_out, int out_size, void* d_ws, size_t ws_size,
                              hipStream_t stream) {
  (void)in_sizes; (void)n_in; (void)out_size;
  const float* values = (const float*)d_in[0];
  const float* keys   = (const float*)d_in[1];
  const float* query  = (const float*)d_in[2];
  const float* Wq = (const float*)d_in[3];  const float* bq = (const float*)d_in[4];
  const float* Wk = (const float*)d_in[5];  const float* bk = (const float*)d_in[6];
  const float* Wv = (const float*)d_in[7];  const float* bv = (const float*)d_in[8];
  const float* Wo = (const float*)d_in[9];  const float* bo = (const float*)d_in[10];
  const float* bp = (const float*)d_in[11]; const float* ep = (const float*)d_in[12];

  u16* ws    = (u16*)d_ws;
  u16* qbuf  = ws;
  u16* kbuf  = ws + (size_t)EL;
  u16* vtbuf = ws + (size_t)2 * EL;
  u16* wb    = ws + (size_t)3 * EL;            // 7*WEL of W splits
  u16* xb    = wb + (size_t)7 * WEL;           // X split region
  u16* ctx   = xb;                             // aliases Xh[0] (dead after proj)

  const float* Xsrc[3] = {query, keys, values};
  const float* Bsrc[3] = {bq, bk, bv};
  u16* Dst[3] = {qbuf, kbuf, vtbuf};

  prep_w_kernel<<<dim3(256, 4), 256, 0, stream>>>(Wq, Wk, Wv, Wo, wb);

  const bool par = ws_size >= (size_t)79167488;   // (9*EL + 7*WEL)*2 bytes
  if (par) {
    ProjArgs a;
    for (int m = 0; m < 3; ++m) {
      u16* xh = xb + (size_t)m * 2 * EL;
      prep_split_kernel<<<4096, 256, 0, stream>>>(Xsrc[m], xh, xh + EL, EL / 4);
      a.Xh[m] = xh; a.Xl[m] = xh + EL;
      a.Wh[m] = wb + (size_t)m * 2 * WEL; a.Wl[m] = wb + (size_t)m * 2 * WEL + WEL;
      a.bias[m] = Bsrc[m]; a.dst[m] = Dst[m]; a.trans[m] = (m == 2);
    }
    proj_kernel<<<dim3(64, 4, 3), 256, 0, stream>>>(a, bp, ep);
  } else {
    for (int m = 0; m < 3; ++m) {
      prep_split_kernel<<<4096, 256, 0, stream>>>(Xsrc[m], xb, xb + EL, EL / 4);
      ProjArgs a = {};
      a.Xh[0] = xb; a.Xl[0] = xb + EL;
      a.Wh[0] = wb + (size_t)m * 2 * WEL; a.Wl[0] = wb + (size_t)m * 2 * WEL + WEL;
      a.bias[0] = Bsrc[m]; a.dst[0] = Dst[m]; a.trans[0] = (m == 2);
      proj_kernel<<<dim3(64, 4, 1), 256, 0, stream>>>(a, bp, ep);
    }
  }

  attn_kernel<<<dim3(16, 8, 4), 256, 0, stream>>>(qbuf, kbuf, vtbuf, ctx);
  outproj_kernel<<<dim3(64, 4), 256, 0, stream>>>(ctx, wb + (size_t)6 * WEL, bo,
                                                  (float*)d_out);
}

// Round 3
// 292.299 us; speedup vs baseline: 1.1623x; 1.0966x over previous
//
#include <hip/hip_runtime.h>
#include <hip/hip_bf16.h>
#include <cstdint>
#include <cstddef>

// ---------------------------------------------------------------------------
// QuantizedMultiheadAttention  (N=4, T=2048, E=512, H=8, D=64)
//
//  prep_w / prep_split : fp32 -> split-bf16 (h + l) buffers, computed ONCE
//  proj_kernel  : q/k/v = quantize(X@W^T+b), 3-pass split-bf16 MFMA 32x32x16,
//                 128x128 tiles, global_load_lds(16B), XOR-swizzled LDS.
//                 v stored pre-transposed [N,H,D,T].
//  attn_kernel  : barrier-free flash attention; S^T trick (A=K,B=Q) puts each
//                 Q-row's scores in one lane -> no-max softmax = per-lane adds.
//                 K/V fragments REGISTER-DOUBLE-BUFFERED from global (R3: the
//                 R2 version was latency-bound: loads fed MFMAs directly).
//  outproj      : out = ctx@Wo^T + bo (bf16 MFMA, fp32 out)
// ---------------------------------------------------------------------------

typedef __attribute__((ext_vector_type(8))) __bf16 bf16x8;
typedef __attribute__((ext_vector_type(16))) float f32x16;
typedef unsigned short u16;

#define EL  4194304   // 4*2048*512 elements (one X-like matrix / qkv buf)
#define WEL 262144    // 512*512

static __device__ __forceinline__ u16 f2bf(float x) {
  unsigned u = __float_as_uint(x);
  u += 0x7fffu + ((u >> 16) & 1u);           // round-to-nearest-even
  return (u16)(u >> 16);
}
static __device__ __forceinline__ float bf2f(u16 h) {
  return __uint_as_float(((unsigned)h) << 16);
}
static __device__ __forceinline__ void split2(float x, u16& h, u16& l) {
  u16 hb = f2bf(x); h = hb; l = f2bf(x - bf2f(hb));   // residual exact in fp32
}
static __device__ __forceinline__ void gl_lds16(const void* g, void* l) {
  __builtin_amdgcn_global_load_lds(
      (__attribute__((address_space(1))) void*)g,
      (__attribute__((address_space(3))) void*)l, 16, 0, 0);
}

// ---------------------------------------------------------------------------
// prep kernels: one-time fp32 -> bf16 split conversions
// ---------------------------------------------------------------------------
__global__ __launch_bounds__(256) void prep_split_kernel(
    const float* __restrict__ src, u16* __restrict__ dh, u16* __restrict__ dl,
    int n4)
{
  int i = blockIdx.x * 256 + threadIdx.x;
  if (i >= n4) return;
  float4 v = ((const float4*)src)[i];
  ushort4 h, l;
  split2(v.x, h.x, l.x); split2(v.y, h.y, l.y);
  split2(v.z, h.z, l.z); split2(v.w, h.w, l.w);
  ((ushort4*)dh)[i] = h; ((ushort4*)dl)[i] = l;
}

struct PrepArgs { const float* src[3]; u16* dh[3]; u16* dl[3]; };

__global__ __launch_bounds__(256) void prep_split3_kernel(PrepArgs a)
{
  const int m = blockIdx.y;
  int i = blockIdx.x * 256 + threadIdx.x;
  float4 v = ((const float4*)a.src[m])[i];
  ushort4 h, l;
  split2(v.x, h.x, l.x); split2(v.y, h.y, l.y);
  split2(v.z, h.z, l.z); split2(v.w, h.w, l.w);
  ((ushort4*)a.dh[m])[i] = h; ((ushort4*)a.dl[m])[i] = l;
}

__global__ __launch_bounds__(256) void prep_w_kernel(
    const float* __restrict__ Wq, const float* __restrict__ Wk,
    const float* __restrict__ Wv, const float* __restrict__ Wo,
    u16* __restrict__ wb)
{
  const int y = blockIdx.y;
  const float* src = (y == 0) ? Wq : (y == 1) ? Wk : (y == 2) ? Wv : Wo;
  int i = blockIdx.x * 256 + threadIdx.x;     // 65536 threads = WEL/4
  float4 v = ((const float4*)src)[i];
  if (y < 3) {
    ushort4 h, l;
    split2(v.x, h.x, l.x); split2(v.y, h.y, l.y);
    split2(v.z, h.z, l.z); split2(v.w, h.w, l.w);
    ((ushort4*)(wb + (size_t)y * 2 * WEL))[i] = h;
    ((ushort4*)(wb + (size_t)y * 2 * WEL + WEL))[i] = l;
  } else {
    ushort4 h;
    h.x = f2bf(v.x); h.y = f2bf(v.y); h.z = f2bf(v.z); h.w = f2bf(v.w);
    ((ushort4*)(wb + (size_t)6 * WEL))[i] = h;
  }
}

// ---------------------------------------------------------------------------
// proj: C = quantize(X@W^T + b), 3-pass split-bf16, 128x128 tile, BK=32
// ---------------------------------------------------------------------------
struct ProjArgs {
  const u16* Xh[3]; const u16* Xl[3];
  const u16* Wh[3]; const u16* Wl[3];
  const float* bias[3];
  u16* dst[3];
  int trans[3];
};

__global__ __launch_bounds__(256) void proj_kernel(ProjArgs args,
    const float* __restrict__ bparam, const float* __restrict__ eparam)
{
  __shared__ u16 sm[17408];                 // 34.8 KB (staging 32 KB + T-epilogue)
  u16* const Ah = sm;
  u16* const Al = sm + 4096;
  u16* const Bh = sm + 8192;
  u16* const Bl = sm + 12288;

  const int z = blockIdx.z;
  const u16* __restrict__ Xh = args.Xh[z];
  const u16* __restrict__ Xl = args.Xl[z];
  const u16* __restrict__ Wh = args.Wh[z];
  const u16* __restrict__ Wl = args.Wl[z];
  const float* __restrict__ bias = args.bias[z];
  u16* __restrict__ dst = args.dst[z];
  const int trans = args.trans[z];

  const int tid  = threadIdx.x;
  const int lane = tid & 63;
  const int wave = tid >> 6;
  const int lam  = lane & 31;
  const int hl   = lane >> 5;
  const int wm   = wave & 1;
  const int wn   = wave >> 1;
  const int mbase = blockIdx.x * 128;
  const int nbase = blockIdx.y * 128;

  // staging: chunk c=tid and c=tid+256 per tile; row=c>>2, kc=((c&3)-(c>>4))&3
  const int srow = tid >> 2;
  const int skc  = ((tid & 3) - (tid >> 4)) & 3;
  const u16* gAh = Xh + (size_t)(mbase + srow) * 512 + skc * 8;
  const u16* gAl = Xl + (size_t)(mbase + srow) * 512 + skc * 8;
  const u16* gBh = Wh + (size_t)(nbase + srow) * 512 + skc * 8;
  const u16* gBl = Wl + (size_t)(nbase + srow) * 512 + skc * 8;
  const int lo = tid * 8;                   // chunk byte/2 offset in each tile

  // fragment LDS byte offsets (XOR-swizzled: pos = (kchunk + (row>>2)) & 3)
  int offA[2][2], offB[2][2];
#pragma unroll
  for (int f = 0; f < 2; ++f)
#pragma unroll
    for (int kk = 0; kk < 2; ++kk) {
      int m = wm * 64 + f * 32 + lam;
      offA[f][kk] = m * 64 + (((2 * kk + hl) + (m >> 2)) & 3) * 16;
      int nn = wn * 64 + f * 32 + lam;
      offB[f][kk] = nn * 64 + (((2 * kk + hl) + (nn >> 2)) & 3) * 16;
    }

  f32x16 acc[2][2];
#pragma unroll
  for (int a = 0; a < 2; ++a)
#pragma unroll
    for (int b = 0; b < 2; ++b)
#pragma unroll
      for (int i = 0; i < 16; ++i) acc[a][b][i] = 0.f;

  for (int kt = 0; kt < 512; kt += 32) {
    __syncthreads();                        // prior frag reads done
    gl_lds16(gAh + kt,             Ah + lo);
    gl_lds16(gAh + kt + 64 * 512,  Ah + lo + 2048);
    gl_lds16(gAl + kt,             Al + lo);
    gl_lds16(gAl + kt + 64 * 512,  Al + lo + 2048);
    gl_lds16(gBh + kt,             Bh + lo);
    gl_lds16(gBh + kt + 64 * 512,  Bh + lo + 2048);
    gl_lds16(gBl + kt,             Bl + lo);
    gl_lds16(gBl + kt + 64 * 512,  Bl + lo + 2048);
    __syncthreads();                        // vmcnt(0) drained before barrier

    bf16x8 fAh[2][2], fAl[2][2], fBh[2][2], fBl[2][2];
#pragma unroll
    for (int f = 0; f < 2; ++f)
#pragma unroll
      for (int kk = 0; kk < 2; ++kk) {
        fAh[f][kk] = *(const bf16x8*)((const char*)Ah + offA[f][kk]);
        fAl[f][kk] = *(const bf16x8*)((const char*)Al + offA[f][kk]);
        fBh[f][kk] = *(const bf16x8*)((const char*)Bh + offB[f][kk]);
        fBl[f][kk] = *(const bf16x8*)((const char*)Bl + offB[f][kk]);
      }
#pragma unroll
    for (int mf = 0; mf < 2; ++mf)
#pragma unroll
      for (int nf = 0; nf < 2; ++nf)
#pragma unroll
        for (int kk = 0; kk < 2; ++kk) {
          acc[mf][nf] = __builtin_amdgcn_mfma_f32_32x32x16_bf16(
              fAh[mf][kk], fBh[nf][kk], acc[mf][nf], 0, 0, 0);
          acc[mf][nf] = __builtin_amdgcn_mfma_f32_32x32x16_bf16(
              fAh[mf][kk], fBl[nf][kk], acc[mf][nf], 0, 0, 0);
          acc[mf][nf] = __builtin_amdgcn_mfma_f32_32x32x16_bf16(
              fAl[mf][kk], fBh[nf][kk], acc[mf][nf], 0, 0, 0);
        }
  }

  // quantize epilogue
  const float bq   = fminf(fmaxf(bparam[0], 1.0f), 8.0f);
  const float e    = eparam[0];
  const float s    = exp2f(e);
  const float invs = exp2f(-e);
  const float qlo  = -exp2f(bq - 1.0f);
  const float qhi  = exp2f(bq - 1.0f) - 1.0f;
  const int nidx = mbase >> 11;             // batch
  const int tb   = mbase & 2047;            // t base
  const int hb   = nbase >> 6;              // head base (2 heads per col-tile)

  if (!trans) {
#pragma unroll
    for (int mf = 0; mf < 2; ++mf)
#pragma unroll
      for (int nf = 0; nf < 2; ++nf)
#pragma unroll
        for (int reg = 0; reg < 16; ++reg) {
          int col = wn * 64 + nf * 32 + lam;
          int row = wm * 64 + mf * 32 + (reg & 3) + 8 * (reg >> 2) + 4 * hl;
          float v = acc[mf][nf][reg] + bias[nbase + col];
          float qv = floorf(fminf(fmaxf(v * invs, qlo), qhi)) * s;
          dst[((size_t)(nidx * 8 + hb + (col >> 6)) * 2048 + tb + row) * 64 +
              (col & 63)] = f2bf(qv);
        }
  } else {
    __syncthreads();                        // staging LDS reads done everywhere
#pragma unroll
    for (int mf = 0; mf < 2; ++mf)
#pragma unroll
      for (int nf = 0; nf < 2; ++nf)
#pragma unroll
        for (int reg = 0; reg < 16; ++reg) {
          int col = wn * 64 + nf * 32 + lam;
          int row = wm * 64 + mf * 32 + (reg & 3) + 8 * (reg >> 2) + 4 * hl;
          float v = acc[mf][nf][reg] + bias[nbase + col];
          float qv = floorf(fminf(fmaxf(v * invs, qlo), qhi)) * s;
          sm[col * 136 + row] = f2bf(qv);   // [d-ish col][t row], stride 136
        }
    __syncthreads();
    const int r = tid >> 1, half = tid & 1;
    const u16* sp = sm + r * 136 + half * 64;
    u16* gp = dst + ((size_t)(nidx * 8 + hb + (r >> 6)) * 64 + (r & 63)) * 2048 +
              tb + half * 64;
#pragma unroll
    for (int i = 0; i < 8; ++i)
      *(uint4*)(gp + i * 8) = *(const uint4*)(sp + i * 8);
  }
}

// ---------------------------------------------------------------------------
// attn: barrier-free flash attention, 128 q-rows/block (32 per wave).
// Register double-buffer: prefetch K/V fragments for tile t+1 while tile t
// computes (R2 was latency-bound on load->MFMA dependencies).
// ---------------------------------------------------------------------------
__global__ __launch_bounds__(256, 2) void attn_kernel(
    const u16* __restrict__ qbuf, const u16* __restrict__ kbuf,
    const u16* __restrict__ vtbuf, u16* __restrict__ ctx)
{
  __shared__ u16 P[8192];                   // 16 KB, 4 KB per wave (private)
  const int tid  = threadIdx.x;
  const int wave = tid >> 6;
  const int lane = tid & 63;
  const int lam  = lane & 31;
  const int hl   = lane >> 5;
  const int qt = blockIdx.x, hd = blockIdx.y, n = blockIdx.z;
  const int nh = n * 8 + hd;
  const int qbase = qt * 128 + wave * 32;

  const u16* Qp = qbuf + ((size_t)nh * 2048 + qbase) * 64;
  const u16* Kp = kbuf + (size_t)nh * 131072;
  const u16* Vp = vtbuf + (size_t)nh * 131072;

  bf16x8 qf[4];                             // B-operand: B[n=lam][k=dk*16+hl*8+j]
#pragma unroll
  for (int dk = 0; dk < 4; ++dk)
    qf[dk] = *(const bf16x8*)(Qp + lam * 64 + dk * 16 + hl * 8);

  const float sc = (float)(1.4426950408889634 / 22.627416997969522); // log2e/sqrt(512)

  char* const Pwb = (char*)(P + wave * 2048);
  int pwoff[2][4], proff[4];
#pragma unroll
  for (int kf = 0; kf < 2; ++kf)
#pragma unroll
    for (int r4 = 0; r4 < 4; ++r4)
      pwoff[kf][r4] = lam * 128 + ((kf * 4 + r4 + lam) & 7) * 16 + hl * 8;
#pragma unroll
  for (int kk = 0; kk < 4; ++kk)
    proff[kk] = lam * 128 + ((2 * kk + hl + lam) & 7) * 16;

  float l_acc = 0.f;
  f32x16 O[2];
#pragma unroll
  for (int a = 0; a < 2; ++a)
#pragma unroll
    for (int i = 0; i < 16; ++i) O[a][i] = 0.f;

  // K/V base pointers (per-lane invariant parts)
  const u16* Kb = Kp + (size_t)lam * 64 + hl * 8;     // + (kt+kf*32)*64 + dk*16
  const u16* Vb0 = Vp + (size_t)lam * 2048 + hl * 8;  // nf=0: + kt + kk*16
  const u16* Vb1 = Vp + (size_t)(32 + lam) * 2048 + hl * 8;

  auto loadKV = [&](bf16x8 (&Kf)[2][4], bf16x8 (&Vf)[2][4], int kt) {
#pragma unroll
    for (int kf = 0; kf < 2; ++kf) {
      const u16* Kr = Kb + (size_t)(kt + kf * 32) * 64;
#pragma unroll
      for (int dk = 0; dk < 4; ++dk)
        Kf[kf][dk] = *(const bf16x8*)(Kr + dk * 16);
    }
#pragma unroll
    for (int kk = 0; kk < 4; ++kk) {
      Vf[0][kk] = *(const bf16x8*)(Vb0 + kt + kk * 16);
      Vf[1][kk] = *(const bf16x8*)(Vb1 + kt + kk * 16);
    }
  };

  auto tileCompute = [&](const bf16x8 (&Kf)[2][4], const bf16x8 (&Vf)[2][4]) {
#pragma unroll
    for (int kf = 0; kf < 2; ++kf) {
      f32x16 S;
#pragma unroll
      for (int i = 0; i < 16; ++i) S[i] = 0.f;
#pragma unroll
      for (int dk = 0; dk < 4; ++dk)
        S = __builtin_amdgcn_mfma_f32_32x32x16_bf16(Kf[kf][dk], qf[dk], S, 0, 0, 0);
      // no-max softmax partials: all 16 scores belong to q-row lam
#pragma unroll
      for (int r4 = 0; r4 < 4; ++r4) {
        float p0 = __builtin_amdgcn_exp2f(S[r4 * 4 + 0] * sc);
        float p1 = __builtin_amdgcn_exp2f(S[r4 * 4 + 1] * sc);
        float p2 = __builtin_amdgcn_exp2f(S[r4 * 4 + 2] * sc);
        float p3 = __builtin_amdgcn_exp2f(S[r4 * 4 + 3] * sc);
        l_acc += (p0 + p1) + (p2 + p3);
        // truncating bf16x2 pack via byte-perm (1 op per pair, bias ~2^-9)
        uint2 u;
        u.x = __builtin_amdgcn_perm(__float_as_uint(p1), __float_as_uint(p0),
                                    0x07060302u);
        u.y = __builtin_amdgcn_perm(__float_as_uint(p3), __float_as_uint(p2),
                                    0x07060302u);
        *(uint2*)(Pwb + pwoff[kf][r4]) = u;  // P[qrow=lam][4 consecutive keys]
      }
    }
    // O += P V   (A = P rows from wave-private LDS, B = V^T fragment regs)
    bf16x8 pa[4];
#pragma unroll
    for (int kk = 0; kk < 4; ++kk)
      pa[kk] = *(const bf16x8*)(Pwb + proff[kk]);
#pragma unroll
    for (int nf = 0; nf < 2; ++nf)
#pragma unroll
      for (int kk = 0; kk < 4; ++kk)
        O[nf] = __builtin_amdgcn_mfma_f32_32x32x16_bf16(pa[kk], Vf[nf][kk],
                                                        O[nf], 0, 0, 0);
  };

  bf16x8 K0[2][4], V0[2][4], K1[2][4], V1[2][4];
  loadKV(K0, V0, 0);
  for (int kt = 0; kt < 2048; kt += 128) {
    loadKV(K1, V1, kt + 64);
    tileCompute(K0, V0);                     // tile kt
    loadKV(K0, V0, (kt + 128) & 2047);       // wraps to 0 on last (discarded)
    tileCompute(K1, V1);                     // tile kt+64
  }

  // epilogue: one cross-lane combine, normalize, store ctx [N,T,E]
  l_acc += __shfl_xor(l_acc, 32);
  const float rinv = 1.0f / l_acc;          // lane holds 1/l[qrow=lam]
  float rv[16];
#pragma unroll
  for (int reg = 0; reg < 16; ++reg)
    rv[reg] = __shfl(rinv, (reg & 3) + 8 * (reg >> 2) + 4 * hl);
#pragma unroll
  for (int nf = 0; nf < 2; ++nf)
#pragma unroll
    for (int reg = 0; reg < 16; ++reg) {
      int row = (reg & 3) + 8 * (reg >> 2) + 4 * hl;
      float v = O[nf][reg] * rv[reg];
      ctx[((size_t)n * 2048 + qbase + row) * 512 + hd * 64 + nf * 32 + lam] =
          f2bf(v);
    }
}

// ---------------------------------------------------------------------------
// outproj: out = ctx @ Wo^T + bo  (single-pass bf16, fp32 out)
// ---------------------------------------------------------------------------
__global__ __launch_bounds__(256) void outproj_kernel(
    const u16* __restrict__ ctxb, const u16* __restrict__ Wob,
    const float* __restrict__ bias, float* __restrict__ out)
{
  __shared__ u16 sm[8192];
  u16* const As = sm;
  u16* const Bs = sm + 4096;

  const int tid  = threadIdx.x;
  const int lane = tid & 63;
  const int wave = tid >> 6;
  const int lam  = lane & 31;
  const int hl   = lane >> 5;
  const int wm   = wave & 1;
  const int wn   = wave >> 1;
  const int mbase = blockIdx.x * 128;
  const int nbase = blockIdx.y * 128;

  const int srow = tid >> 2;
  const int skc  = ((tid & 3) - (tid >> 4)) & 3;
  const u16* gA = ctxb + (size_t)(mbase + srow) * 512 + skc * 8;
  const u16* gB = Wob  + (size_t)(nbase + srow) * 512 + skc * 8;
  const int lo = tid * 8;

  int offA[2][2], offB[2][2];
#pragma unroll
  for (int f = 0; f < 2; ++f)
#pragma unroll
    for (int kk = 0; kk < 2; ++kk) {
      int m = wm * 64 + f * 32 + lam;
      offA[f][kk] = m * 64 + (((2 * kk + hl) + (m >> 2)) & 3) * 16;
      int nn = wn * 64 + f * 32 + lam;
      offB[f][kk] = nn * 64 + (((2 * kk + hl) + (nn >> 2)) & 3) * 16;
    }

  f32x16 acc[2][2];
#pragma unroll
  for (int a = 0; a < 2; ++a)
#pragma unroll
    for (int b = 0; b < 2; ++b)
#pragma unroll
      for (int i = 0; i < 16; ++i) acc[a][b][i] = 0.f;

  for (int kt = 0; kt < 512; kt += 32) {
    __syncthreads();
    gl_lds16(gA + kt,            As + lo);
    gl_lds16(gA + kt + 64 * 512, As + lo + 2048);
    gl_lds16(gB + kt,            Bs + lo);
    gl_lds16(gB + kt + 64 * 512, Bs + lo + 2048);
    __syncthreads();

    bf16x8 fA[2][2], fB[2][2];
#pragma unroll
    for (int f = 0; f < 2; ++f)
#pragma unroll
      for (int kk = 0; kk < 2; ++kk) {
        fA[f][kk] = *(const bf16x8*)((const char*)As + offA[f][kk]);
        fB[f][kk] = *(const bf16x8*)((const char*)Bs + offB[f][kk]);
      }
#pragma unroll
    for (int mf = 0; mf < 2; ++mf)
#pragma unroll
      for (int nf = 0; nf < 2; ++nf)
#pragma unroll
        for (int kk = 0; kk < 2; ++kk)
          acc[mf][nf] = __builtin_amdgcn_mfma_f32_32x32x16_bf16(
              fA[mf][kk], fB[nf][kk], acc[mf][nf], 0, 0, 0);
  }

#pragma unroll
  for (int mf = 0; mf < 2; ++mf)
#pragma unroll
    for (int nf = 0; nf < 2; ++nf)
#pragma unroll
      for (int reg = 0; reg < 16; ++reg) {
        int col = wn * 64 + nf * 32 + lam;
        int row = wm * 64 + mf * 32 + (reg & 3) + 8 * (reg >> 2) + 4 * hl;
        out[(size_t)(mbase + row) * 512 + nbase + col] =
            acc[mf][nf][reg] + bias[nbase + col];
      }
}

// ---------------------------------------------------------------------------
extern "C" void kernel_launch(void* const* d_in, const int* in_sizes, int n_in,
                              void* d_out, int out_size, void* d_ws, size_t ws_size,
                              hipStream_t stream) {
  (void)in_sizes; (void)n_in; (void)out_size;
  const float* values = (const float*)d_in[0];
  const float* keys   = (const float*)d_in[1];
  const float* query  = (const float*)d_in[2];
  const float* Wq = (const float*)d_in[3];  const float* bq = (const float*)d_in[4];
  const float* Wk = (const float*)d_in[5];  const float* bk = (const float*)d_in[6];
  const float* Wv = (const float*)d_in[7];  const float* bv = (const float*)d_in[8];
  const float* Wo = (const float*)d_in[9];  const float* bo = (const float*)d_in[10];
  const float* bp = (const float*)d_in[11]; const float* ep = (const float*)d_in[12];

  u16* ws    = (u16*)d_ws;
  u16* qbuf  = ws;
  u16* kbuf  = ws + (size_t)EL;
  u16* vtbuf = ws + (size_t)2 * EL;
  u16* wb    = ws + (size_t)3 * EL;            // 7*WEL of W splits
  u16* xb    = wb + (size_t)7 * WEL;           // X split region
  u16* ctx   = xb;                             // aliases Xh[0] (dead after proj)

  const float* Xsrc[3] = {query, keys, values};
  const float* Bsrc[3] = {bq, bk, bv};
  u16* Dst[3] = {qbuf, kbuf, vtbuf};

  prep_w_kernel<<<dim3(256, 4), 256, 0, stream>>>(Wq, Wk, Wv, Wo, wb);

  const bool par = ws_size >= (size_t)79167488;   // (9*EL + 7*WEL)*2 bytes
  if (par) {
    ProjArgs a;
    PrepArgs p;
    for (int m = 0; m < 3; ++m) {
      u16* xh = xb + (size_t)m * 2 * EL;
      p.src[m] = Xsrc[m]; p.dh[m] = xh; p.dl[m] = xh + EL;
      a.Xh[m] = xh; a.Xl[m] = xh + EL;
      a.Wh[m] = wb + (size_t)m * 2 * WEL; a.Wl[m] = wb + (size_t)m * 2 * WEL + WEL;
      a.bias[m] = Bsrc[m]; a.dst[m] = Dst[m]; a.trans[m] = (m == 2);
    }
    prep_split3_kernel<<<dim3(4096, 3), 256, 0, stream>>>(p);
    proj_kernel<<<dim3(64, 4, 3), 256, 0, stream>>>(a, bp, ep);
  } else {
    for (int m = 0; m < 3; ++m) {
      prep_split_kernel<<<4096, 256, 0, stream>>>(Xsrc[m], xb, xb + EL, EL / 4);
      ProjArgs a = {};
      a.Xh[0] = xb; a.Xl[0] = xb + EL;
      a.Wh[0] = wb + (size_t)m * 2 * WEL; a.Wl[0] = wb + (size_t)m * 2 * WEL + WEL;
      a.bias[0] = Bsrc[m]; a.dst[0] = Dst[m]; a.trans[0] = (m == 2);
      proj_kernel<<<dim3(64, 4, 1), 256, 0, stream>>>(a, bp, ep);
    }
  }

  attn_kernel<<<dim3(16, 8, 4), 256, 0, stream>>>(qbuf, kbuf, vtbuf, ctx);
  outproj_kernel<<<dim3(64, 4), 256, 0, stream>>>(ctx, wb + (size_t)6 * WEL, bo,
                                                  (float*)d_out);
}

// Round 4
// 235.816 us; speedup vs baseline: 1.4407x; 1.2395x over previous
//
#include <hip/hip_runtime.h>
#include <hip/hip_bf16.h>
#include <cstdint>
#include <cstddef>

// ---------------------------------------------------------------------------
// QuantizedMultiheadAttention  (N=4, T=2048, E=512, H=8, D=64)
//
//  prep_w / prep_split : fp32 -> split-bf16 (h + l) buffers, computed ONCE
//  proj_kernel  : q/k/v = quantize(X@W^T+b), 3-pass split-bf16 MFMA 32x32x16,
//                 128x128 tiles, global_load_lds(16B), XOR-swizzled LDS.
//                 v stored pre-transposed [N,H,D,T].
//  attn_kernel  : flash attention, R4: K/V staged in LDS via global_load_lds
//                 (R3's register double-buffer was silently defeated by the
//                 compiler, VGPR=88 proved loads sank to uses -> latency-bound).
//                 4 waves share staged K/V; S^T no-max softmax; P C->A layout
//                 transform via half-wave __shfl_xor(32) (no LDS round-trip).
//  outproj      : out = ctx@Wo^T + bo (bf16 MFMA, fp32 out)
// ---------------------------------------------------------------------------

typedef __attribute__((ext_vector_type(8))) __bf16 bf16x8;
typedef __attribute__((ext_vector_type(16))) float f32x16;
typedef __attribute__((ext_vector_type(4))) unsigned u32x4;
typedef unsigned short u16;

#define EL  4194304   // 4*2048*512 elements (one X-like matrix / qkv buf)
#define WEL 262144    // 512*512

static __device__ __forceinline__ u16 f2bf(float x) {
  unsigned u = __float_as_uint(x);
  u += 0x7fffu + ((u >> 16) & 1u);           // round-to-nearest-even
  return (u16)(u >> 16);
}
static __device__ __forceinline__ float bf2f(u16 h) {
  return __uint_as_float(((unsigned)h) << 16);
}
static __device__ __forceinline__ void split2(float x, u16& h, u16& l) {
  u16 hb = f2bf(x); h = hb; l = f2bf(x - bf2f(hb));   // residual exact in fp32
}
static __device__ __forceinline__ void gl_lds16(const void* g, void* l) {
  __builtin_amdgcn_global_load_lds(
      (__attribute__((address_space(1))) void*)g,
      (__attribute__((address_space(3))) void*)l, 16, 0, 0);
}

// ---------------------------------------------------------------------------
// prep kernels: one-time fp32 -> bf16 split conversions
// ---------------------------------------------------------------------------
__global__ __launch_bounds__(256) void prep_split_kernel(
    const float* __restrict__ src, u16* __restrict__ dh, u16* __restrict__ dl,
    int n4)
{
  int i = blockIdx.x * 256 + threadIdx.x;
  if (i >= n4) return;
  float4 v = ((const float4*)src)[i];
  ushort4 h, l;
  split2(v.x, h.x, l.x); split2(v.y, h.y, l.y);
  split2(v.z, h.z, l.z); split2(v.w, h.w, l.w);
  ((ushort4*)dh)[i] = h; ((ushort4*)dl)[i] = l;
}

struct PrepArgs { const float* src[3]; u16* dh[3]; u16* dl[3]; };

__global__ __launch_bounds__(256) void prep_split3_kernel(PrepArgs a)
{
  const int m = blockIdx.y;
  int i = blockIdx.x * 256 + threadIdx.x;
  float4 v = ((const float4*)a.src[m])[i];
  ushort4 h, l;
  split2(v.x, h.x, l.x); split2(v.y, h.y, l.y);
  split2(v.z, h.z, l.z); split2(v.w, h.w, l.w);
  ((ushort4*)a.dh[m])[i] = h; ((ushort4*)a.dl[m])[i] = l;
}

__global__ __launch_bounds__(256) void prep_w_kernel(
    const float* __restrict__ Wq, const float* __restrict__ Wk,
    const float* __restrict__ Wv, const float* __restrict__ Wo,
    u16* __restrict__ wb)
{
  const int y = blockIdx.y;
  const float* src = (y == 0) ? Wq : (y == 1) ? Wk : (y == 2) ? Wv : Wo;
  int i = blockIdx.x * 256 + threadIdx.x;     // 65536 threads = WEL/4
  float4 v = ((const float4*)src)[i];
  if (y < 3) {
    ushort4 h, l;
    split2(v.x, h.x, l.x); split2(v.y, h.y, l.y);
    split2(v.z, h.z, l.z); split2(v.w, h.w, l.w);
    ((ushort4*)(wb + (size_t)y * 2 * WEL))[i] = h;
    ((ushort4*)(wb + (size_t)y * 2 * WEL + WEL))[i] = l;
  } else {
    ushort4 h;
    h.x = f2bf(v.x); h.y = f2bf(v.y); h.z = f2bf(v.z); h.w = f2bf(v.w);
    ((ushort4*)(wb + (size_t)6 * WEL))[i] = h;
  }
}

// ---------------------------------------------------------------------------
// proj: C = quantize(X@W^T + b), 3-pass split-bf16, 128x128 tile, BK=32
// ---------------------------------------------------------------------------
struct ProjArgs {
  const u16* Xh[3]; const u16* Xl[3];
  const u16* Wh[3]; const u16* Wl[3];
  const float* bias[3];
  u16* dst[3];
  int trans[3];
};

__global__ __launch_bounds__(256) void proj_kernel(ProjArgs args,
    const float* __restrict__ bparam, const float* __restrict__ eparam)
{
  __shared__ u16 sm[17408];                 // 34.8 KB (staging 32 KB + T-epilogue)
  u16* const Ah = sm;
  u16* const Al = sm + 4096;
  u16* const Bh = sm + 8192;
  u16* const Bl = sm + 12288;

  const int z = blockIdx.z;
  const u16* __restrict__ Xh = args.Xh[z];
  const u16* __restrict__ Xl = args.Xl[z];
  const u16* __restrict__ Wh = args.Wh[z];
  const u16* __restrict__ Wl = args.Wl[z];
  const float* __restrict__ bias = args.bias[z];
  u16* __restrict__ dst = args.dst[z];
  const int trans = args.trans[z];

  const int tid  = threadIdx.x;
  const int lane = tid & 63;
  const int wave = tid >> 6;
  const int lam  = lane & 31;
  const int hl   = lane >> 5;
  const int wm   = wave & 1;
  const int wn   = wave >> 1;
  const int mbase = blockIdx.x * 128;
  const int nbase = blockIdx.y * 128;

  // staging: chunk c=tid and c=tid+256 per tile; row=c>>2, kc=((c&3)-(c>>4))&3
  const int srow = tid >> 2;
  const int skc  = ((tid & 3) - (tid >> 4)) & 3;
  const u16* gAh = Xh + (size_t)(mbase + srow) * 512 + skc * 8;
  const u16* gAl = Xl + (size_t)(mbase + srow) * 512 + skc * 8;
  const u16* gBh = Wh + (size_t)(nbase + srow) * 512 + skc * 8;
  const u16* gBl = Wl + (size_t)(nbase + srow) * 512 + skc * 8;
  const int lo = tid * 8;                   // chunk byte/2 offset in each tile

  // fragment LDS byte offsets (XOR-swizzled: pos = (kchunk + (row>>2)) & 3)
  int offA[2][2], offB[2][2];
#pragma unroll
  for (int f = 0; f < 2; ++f)
#pragma unroll
    for (int kk = 0; kk < 2; ++kk) {
      int m = wm * 64 + f * 32 + lam;
      offA[f][kk] = m * 64 + (((2 * kk + hl) + (m >> 2)) & 3) * 16;
      int nn = wn * 64 + f * 32 + lam;
      offB[f][kk] = nn * 64 + (((2 * kk + hl) + (nn >> 2)) & 3) * 16;
    }

  f32x16 acc[2][2];
#pragma unroll
  for (int a = 0; a < 2; ++a)
#pragma unroll
    for (int b = 0; b < 2; ++b)
#pragma unroll
      for (int i = 0; i < 16; ++i) acc[a][b][i] = 0.f;

  for (int kt = 0; kt < 512; kt += 32) {
    __syncthreads();                        // prior frag reads done
    gl_lds16(gAh + kt,             Ah + lo);
    gl_lds16(gAh + kt + 64 * 512,  Ah + lo + 2048);
    gl_lds16(gAl + kt,             Al + lo);
    gl_lds16(gAl + kt + 64 * 512,  Al + lo + 2048);
    gl_lds16(gBh + kt,             Bh + lo);
    gl_lds16(gBh + kt + 64 * 512,  Bh + lo + 2048);
    gl_lds16(gBl + kt,             Bl + lo);
    gl_lds16(gBl + kt + 64 * 512,  Bl + lo + 2048);
    __syncthreads();                        // vmcnt(0) drained before barrier

    bf16x8 fAh[2][2], fAl[2][2], fBh[2][2], fBl[2][2];
#pragma unroll
    for (int f = 0; f < 2; ++f)
#pragma unroll
      for (int kk = 0; kk < 2; ++kk) {
        fAh[f][kk] = *(const bf16x8*)((const char*)Ah + offA[f][kk]);
        fAl[f][kk] = *(const bf16x8*)((const char*)Al + offA[f][kk]);
        fBh[f][kk] = *(const bf16x8*)((const char*)Bh + offB[f][kk]);
        fBl[f][kk] = *(const bf16x8*)((const char*)Bl + offB[f][kk]);
      }
#pragma unroll
    for (int mf = 0; mf < 2; ++mf)
#pragma unroll
      for (int nf = 0; nf < 2; ++nf)
#pragma unroll
        for (int kk = 0; kk < 2; ++kk) {
          acc[mf][nf] = __builtin_amdgcn_mfma_f32_32x32x16_bf16(
              fAh[mf][kk], fBh[nf][kk], acc[mf][nf], 0, 0, 0);
          acc[mf][nf] = __builtin_amdgcn_mfma_f32_32x32x16_bf16(
              fAh[mf][kk], fBl[nf][kk], acc[mf][nf], 0, 0, 0);
          acc[mf][nf] = __builtin_amdgcn_mfma_f32_32x32x16_bf16(
              fAl[mf][kk], fBh[nf][kk], acc[mf][nf], 0, 0, 0);
        }
  }

  // quantize epilogue
  const float bq   = fminf(fmaxf(bparam[0], 1.0f), 8.0f);
  const float e    = eparam[0];
  const float s    = exp2f(e);
  const float invs = exp2f(-e);
  const float qlo  = -exp2f(bq - 1.0f);
  const float qhi  = exp2f(bq - 1.0f) - 1.0f;
  const int nidx = mbase >> 11;             // batch
  const int tb   = mbase & 2047;            // t base
  const int hb   = nbase >> 6;              // head base (2 heads per col-tile)

  if (!trans) {
#pragma unroll
    for (int mf = 0; mf < 2; ++mf)
#pragma unroll
      for (int nf = 0; nf < 2; ++nf)
#pragma unroll
        for (int reg = 0; reg < 16; ++reg) {
          int col = wn * 64 + nf * 32 + lam;
          int row = wm * 64 + mf * 32 + (reg & 3) + 8 * (reg >> 2) + 4 * hl;
          float v = acc[mf][nf][reg] + bias[nbase + col];
          float qv = floorf(fminf(fmaxf(v * invs, qlo), qhi)) * s;
          dst[((size_t)(nidx * 8 + hb + (col >> 6)) * 2048 + tb + row) * 64 +
              (col & 63)] = f2bf(qv);
        }
  } else {
    __syncthreads();                        // staging LDS reads done everywhere
#pragma unroll
    for (int mf = 0; mf < 2; ++mf)
#pragma unroll
      for (int nf = 0; nf < 2; ++nf)
#pragma unroll
        for (int reg = 0; reg < 16; ++reg) {
          int col = wn * 64 + nf * 32 + lam;
          int row = wm * 64 + mf * 32 + (reg & 3) + 8 * (reg >> 2) + 4 * hl;
          float v = acc[mf][nf][reg] + bias[nbase + col];
          float qv = floorf(fminf(fmaxf(v * invs, qlo), qhi)) * s;
          sm[col * 136 + row] = f2bf(qv);   // [d-ish col][t row], stride 136
        }
    __syncthreads();
    const int r = tid >> 1, half = tid & 1;
    const u16* sp = sm + r * 136 + half * 64;
    u16* gp = dst + ((size_t)(nidx * 8 + hb + (r >> 6)) * 64 + (r & 63)) * 2048 +
              tb + half * 64;
#pragma unroll
    for (int i = 0; i < 8; ++i)
      *(uint4*)(gp + i * 8) = *(const uint4*)(sp + i * 8);
  }
}

// ---------------------------------------------------------------------------
// attn: flash attention, 128 q-rows/block (32 per wave), K/V LDS-staged.
// LDS layout (per 64x64 tile, 128B rows): chunk j of row r stored at
// position j^(r&7) -> staging slots are lane-ordered (global_load_lds
// constraint) AND frag ds_read_b128 is at most 4-way phase-conflicted.
// P C-layout -> A-layout via __shfl_xor(32): lane (lam,hl) owns key-groups
// g with g&1==hl; each A-frag = one own group + partner's complementary one.
// ---------------------------------------------------------------------------
__global__ __launch_bounds__(256, 2) void attn_kernel(
    const u16* __restrict__ qbuf, const u16* __restrict__ kbuf,
    const u16* __restrict__ vtbuf, u16* __restrict__ ctx)
{
  __shared__ u16 sm[8192];                  // Kt 8KB | Vt 8KB
  u16* const Kt = sm;
  u16* const Vt = sm + 4096;

  const int tid  = threadIdx.x;
  const int wave = tid >> 6;
  const int lane = tid & 63;
  const int lam  = lane & 31;
  const int hl   = lane >> 5;
  const int qt = blockIdx.x, hd = blockIdx.y, n = blockIdx.z;
  const int nh = n * 8 + hd;
  const int qbase = qt * 128 + wave * 32;

  const u16* Qp = qbuf + ((size_t)nh * 2048 + qbase) * 64;
  const u16* Kp = kbuf + (size_t)nh * 131072;
  const u16* Vp = vtbuf + (size_t)nh * 131072;

  bf16x8 qf[4];                             // B-operand: B[n=lam][k=dk*16+hl*8+j]
#pragma unroll
  for (int dk = 0; dk < 4; ++dk)
    qf[dk] = *(const bf16x8*)(Qp + lam * 64 + dk * 16 + hl * 8);

  const float sc = (float)(1.4426950408889634 / 22.627416997969522); // log2e/sqrt(512)

  // staging addresses: slot s in {tid, tid+256}; row=s>>3, j=(s&7)^(row&7)
  const int r0 = tid >> 3;                  // 0..31 ; second slot row = r0+32
  const int j0 = (tid & 7) ^ (r0 & 7);      // same j for both slots (+32 keeps &7)
  const u16* gK0 = Kp + (size_t)r0 * 64 + j0 * 8;          // + kt*64
  const u16* gK1 = Kp + (size_t)(r0 + 32) * 64 + j0 * 8;
  const u16* gV0 = Vp + (size_t)r0 * 2048 + j0 * 8;        // + kt
  const u16* gV1 = Vp + (size_t)(r0 + 32) * 2048 + j0 * 8;
  char* const lK0 = (char*)Kt + tid * 16;
  char* const lK1 = (char*)Kt + tid * 16 + 4096;
  char* const lV0 = (char*)Vt + tid * 16;
  char* const lV1 = (char*)Vt + tid * 16 + 4096;

  // fragment byte offsets, swizzle pos = chunk ^ (lam&7)
  int offK[2][4], offV[2][4];
#pragma unroll
  for (int kf = 0; kf < 2; ++kf)
#pragma unroll
    for (int dk = 0; dk < 4; ++dk)
      offK[kf][dk] = (kf * 32 + lam) * 128 + ((2 * dk + hl) ^ (lam & 7)) * 16;
#pragma unroll
  for (int nf = 0; nf < 2; ++nf)
#pragma unroll
    for (int kk = 0; kk < 4; ++kk)
      offV[nf][kk] = (nf * 32 + lam) * 128 + ((2 * kk + hl) ^ (lam & 7)) * 16;

  float l_acc = 0.f;
  f32x16 O[2];
#pragma unroll
  for (int a = 0; a < 2; ++a)
#pragma unroll
    for (int i = 0; i < 16; ++i) O[a][i] = 0.f;

  for (int kt = 0; kt < 2048; kt += 64) {
    __syncthreads();                        // prior tile's frag reads done
    gl_lds16(gK0 + (size_t)kt * 64, lK0);
    gl_lds16(gK1 + (size_t)kt * 64, lK1);
    gl_lds16(gV0 + kt, lV0);
    gl_lds16(gV1 + kt, lV1);
    __syncthreads();                        // vmcnt(0) drained before barrier

    bf16x8 pfrag[4];
#pragma unroll
    for (int kf = 0; kf < 2; ++kf) {
      f32x16 S;
#pragma unroll
      for (int i = 0; i < 16; ++i) S[i] = 0.f;
#pragma unroll
      for (int dk = 0; dk < 4; ++dk)
        S = __builtin_amdgcn_mfma_f32_32x32x16_bf16(
            *(const bf16x8*)((const char*)Kt + offK[kf][dk]), qf[dk], S, 0, 0, 0);
      // no-max softmax; lane (lam,hl) holds keys of q-row lam, groups g&1==hl
      unsigned pk[4][2];
#pragma unroll
      for (int gh = 0; gh < 4; ++gh) {
        float p0 = __builtin_amdgcn_exp2f(S[4 * gh + 0] * sc);
        float p1 = __builtin_amdgcn_exp2f(S[4 * gh + 1] * sc);
        float p2 = __builtin_amdgcn_exp2f(S[4 * gh + 2] * sc);
        float p3 = __builtin_amdgcn_exp2f(S[4 * gh + 3] * sc);
        l_acc += (p0 + p1) + (p2 + p3);
        pk[gh][0] = __builtin_amdgcn_perm(__float_as_uint(p1),
                                          __float_as_uint(p0), 0x07060302u);
        pk[gh][1] = __builtin_amdgcn_perm(__float_as_uint(p3),
                                          __float_as_uint(p2), 0x07060302u);
      }
      // C->A transform: exchange complementary group with partner lane (^32)
#pragma unroll
      for (int kkl = 0; kkl < 2; ++kkl) {
        unsigned s0 = hl ? pk[2 * kkl][0] : pk[2 * kkl + 1][0];
        unsigned s1 = hl ? pk[2 * kkl][1] : pk[2 * kkl + 1][1];
        unsigned o0 = hl ? pk[2 * kkl + 1][0] : pk[2 * kkl][0];
        unsigned o1 = hl ? pk[2 * kkl + 1][1] : pk[2 * kkl][1];
        unsigned rr0 = (unsigned)__shfl_xor((int)s0, 32);
        unsigned rr1 = (unsigned)__shfl_xor((int)s1, 32);
        u32x4 f;
        f[0] = hl ? rr0 : o0;
        f[1] = hl ? rr1 : o1;
        f[2] = hl ? o0 : rr0;
        f[3] = hl ? o1 : rr1;
        pfrag[kf * 2 + kkl] = __builtin_bit_cast(bf16x8, f);
      }
    }
    // O += P V   (A = P frags, B = V^T rows from LDS)
#pragma unroll
    for (int nf = 0; nf < 2; ++nf)
#pragma unroll
      for (int kk = 0; kk < 4; ++kk)
        O[nf] = __builtin_amdgcn_mfma_f32_32x32x16_bf16(
            pfrag[kk], *(const bf16x8*)((const char*)Vt + offV[nf][kk]),
            O[nf], 0, 0, 0);
  }

  // epilogue: one cross-lane combine, normalize, store ctx [N,T,E]
  l_acc += __shfl_xor(l_acc, 32);
  const float rinv = 1.0f / l_acc;          // lane holds 1/l[qrow=lam]
  float rv[16];
#pragma unroll
  for (int reg = 0; reg < 16; ++reg)
    rv[reg] = __shfl(rinv, (reg & 3) + 8 * (reg >> 2) + 4 * hl);
#pragma unroll
  for (int nf = 0; nf < 2; ++nf)
#pragma unroll
    for (int reg = 0; reg < 16; ++reg) {
      int row = (reg & 3) + 8 * (reg >> 2) + 4 * hl;
      float v = O[nf][reg] * rv[reg];
      ctx[((size_t)n * 2048 + qbase + row) * 512 + hd * 64 + nf * 32 + lam] =
          f2bf(v);
    }
}

// ---------------------------------------------------------------------------
// outproj: out = ctx @ Wo^T + bo  (single-pass bf16, fp32 out)
// ---------------------------------------------------------------------------
__global__ __launch_bounds__(256) void outproj_kernel(
    const u16* __restrict__ ctxb, const u16* __restrict__ Wob,
    const float* __restrict__ bias, float* __restrict__ out)
{
  __shared__ u16 sm[8192];
  u16* const As = sm;
  u16* const Bs = sm + 4096;

  const int tid  = threadIdx.x;
  const int lane = tid & 63;
  const int wave = tid >> 6;
  const int lam  = lane & 31;
  const int hl   = lane >> 5;
  const int wm   = wave & 1;
  const int wn   = wave >> 1;
  const int mbase = blockIdx.x * 128;
  const int nbase = blockIdx.y * 128;

  const int srow = tid >> 2;
  const int skc  = ((tid & 3) - (tid >> 4)) & 3;
  const u16* gA = ctxb + (size_t)(mbase + srow) * 512 + skc * 8;
  const u16* gB = Wob  + (size_t)(nbase + srow) * 512 + skc * 8;
  const int lo = tid * 8;

  int offA[2][2], offB[2][2];
#pragma unroll
  for (int f = 0; f < 2; ++f)
#pragma unroll
    for (int kk = 0; kk < 2; ++kk) {
      int m = wm * 64 + f * 32 + lam;
      offA[f][kk] = m * 64 + (((2 * kk + hl) + (m >> 2)) & 3) * 16;
      int nn = wn * 64 + f * 32 + lam;
      offB[f][kk] = nn * 64 + (((2 * kk + hl) + (nn >> 2)) & 3) * 16;
    }

  f32x16 acc[2][2];
#pragma unroll
  for (int a = 0; a < 2; ++a)
#pragma unroll
    for (int b = 0; b < 2; ++b)
#pragma unroll
      for (int i = 0; i < 16; ++i) acc[a][b][i] = 0.f;

  for (int kt = 0; kt < 512; kt += 32) {
    __syncthreads();
    gl_lds16(gA + kt,            As + lo);
    gl_lds16(gA + kt + 64 * 512, As + lo + 2048);
    gl_lds16(gB + kt,            Bs + lo);
    gl_lds16(gB + kt + 64 * 512, Bs + lo + 2048);
    __syncthreads();

    bf16x8 fA[2][2], fB[2][2];
#pragma unroll
    for (int f = 0; f < 2; ++f)
#pragma unroll
      for (int kk = 0; kk < 2; ++kk) {
        fA[f][kk] = *(const bf16x8*)((const char*)As + offA[f][kk]);
        fB[f][kk] = *(const bf16x8*)((const char*)Bs + offB[f][kk]);
      }
#pragma unroll
    for (int mf = 0; mf < 2; ++mf)
#pragma unroll
      for (int nf = 0; nf < 2; ++nf)
#pragma unroll
        for (int kk = 0; kk < 2; ++kk)
          acc[mf][nf] = __builtin_amdgcn_mfma_f32_32x32x16_bf16(
              fA[mf][kk], fB[nf][kk], acc[mf][nf], 0, 0, 0);
  }

#pragma unroll
  for (int mf = 0; mf < 2; ++mf)
#pragma unroll
    for (int nf = 0; nf < 2; ++nf)
#pragma unroll
      for (int reg = 0; reg < 16; ++reg) {
        int col = wn * 64 + nf * 32 + lam;
        int row = wm * 64 + mf * 32 + (reg & 3) + 8 * (reg >> 2) + 4 * hl;
        out[(size_t)(mbase + row) * 512 + nbase + col] =
            acc[mf][nf][reg] + bias[nbase + col];
      }
}

// ---------------------------------------------------------------------------
extern "C" void kernel_launch(void* const* d_in, const int* in_sizes, int n_in,
                              void* d_out, int out_size, void* d_ws, size_t ws_size,
                              hipStream_t stream) {
  (void)in_sizes; (void)n_in; (void)out_size;
  const float* values = (const float*)d_in[0];
  const float* keys   = (const float*)d_in[1];
  const float* query  = (const float*)d_in[2];
  const float* Wq = (const float*)d_in[3];  const float* bq = (const float*)d_in[4];
  const float* Wk = (const float*)d_in[5];  const float* bk = (const float*)d_in[6];
  const float* Wv = (const float*)d_in[7];  const float* bv = (const float*)d_in[8];
  const float* Wo = (const float*)d_in[9];  const float* bo = (const float*)d_in[10];
  const float* bp = (const float*)d_in[11]; const float* ep = (const float*)d_in[12];

  u16* ws    = (u16*)d_ws;
  u16* qbuf  = ws;
  u16* kbuf  = ws + (size_t)EL;
  u16* vtbuf = ws + (size_t)2 * EL;
  u16* wb    = ws + (size_t)3 * EL;            // 7*WEL of W splits
  u16* xb    = wb + (size_t)7 * WEL;           // X split region
  u16* ctx   = xb;                             // aliases Xh[0] (dead after proj)

  const float* Xsrc[3] = {query, keys, values};
  const float* Bsrc[3] = {bq, bk, bv};
  u16* Dst[3] = {qbuf, kbuf, vtbuf};

  prep_w_kernel<<<dim3(256, 4), 256, 0, stream>>>(Wq, Wk, Wv, Wo, wb);

  const bool par = ws_size >= (size_t)79167488;   // (9*EL + 7*WEL)*2 bytes
  if (par) {
    ProjArgs a;
    PrepArgs p;
    for (int m = 0; m < 3; ++m) {
      u16* xh = xb + (size_t)m * 2 * EL;
      p.src[m] = Xsrc[m]; p.dh[m] = xh; p.dl[m] = xh + EL;
      a.Xh[m] = xh; a.Xl[m] = xh + EL;
      a.Wh[m] = wb + (size_t)m * 2 * WEL; a.Wl[m] = wb + (size_t)m * 2 * WEL + WEL;
      a.bias[m] = Bsrc[m]; a.dst[m] = Dst[m]; a.trans[m] = (m == 2);
    }
    prep_split3_kernel<<<dim3(4096, 3), 256, 0, stream>>>(p);
    proj_kernel<<<dim3(64, 4, 3), 256, 0, stream>>>(a, bp, ep);
  } else {
    for (int m = 0; m < 3; ++m) {
      prep_split_kernel<<<4096, 256, 0, stream>>>(Xsrc[m], xb, xb + EL, EL / 4);
      ProjArgs a = {};
      a.Xh[0] = xb; a.Xl[0] = xb + EL;
      a.Wh[0] = wb + (size_t)m * 2 * WEL; a.Wl[0] = wb + (size_t)m * 2 * WEL + WEL;
      a.bias[0] = Bsrc[m]; a.dst[0] = Dst[m]; a.trans[0] = (m == 2);
      proj_kernel<<<dim3(64, 4, 1), 256, 0, stream>>>(a, bp, ep);
    }
  }

  attn_kernel<<<dim3(16, 8, 4), 256, 0, stream>>>(qbuf, kbuf, vtbuf, ctx);
  outproj_kernel<<<dim3(64, 4), 256, 0, stream>>>(ctx, wb + (size_t)6 * WEL, bo,
                                                  (float*)d_out);
}

// Round 5
// 228.160 us; speedup vs baseline: 1.4891x; 1.0336x over previous
//
#include <hip/hip_runtime.h>
#include <hip/hip_bf16.h>
#include <cstdint>
#include <cstddef>

// ---------------------------------------------------------------------------
// QuantizedMultiheadAttention  (N=4, T=2048, E=512, H=8, D=64)
//
//  prep_w / prep_split : fp32 -> split-bf16 (h + l) buffers, computed ONCE
//  proj_kernel  : q/k/v = quantize(X@W^T+b), 3-pass split-bf16 MFMA 32x32x16,
//                 128x128 tiles, global_load_lds(16B), XOR-swizzled LDS.
//                 v stored pre-transposed [N,H,D,T].
//  attn_kernel  : R5 key-split waves: each wave stages + consumes its OWN
//                 64-key K/V tile (frag reads 1:1 with staging; R4 had 4x
//                 cross-wave duplication -> LDS-BW-bound), computes all 64
//                 q-rows of the block, cross-wave O reduction once at end.
//                 S^T no-max softmax; P C->A transform via __shfl_xor(32).
//                 Split into 2 dispatches for rocprof top-5 visibility.
//  outproj      : out = ctx@Wo^T + bo (bf16 MFMA, fp32 out)
// ---------------------------------------------------------------------------

typedef __attribute__((ext_vector_type(8))) __bf16 bf16x8;
typedef __attribute__((ext_vector_type(16))) float f32x16;
typedef __attribute__((ext_vector_type(4))) unsigned u32x4;
typedef unsigned short u16;

#define EL  4194304   // 4*2048*512 elements (one X-like matrix / qkv buf)
#define WEL 262144    // 512*512

static __device__ __forceinline__ u16 f2bf(float x) {
  unsigned u = __float_as_uint(x);
  u += 0x7fffu + ((u >> 16) & 1u);           // round-to-nearest-even
  return (u16)(u >> 16);
}
static __device__ __forceinline__ float bf2f(u16 h) {
  return __uint_as_float(((unsigned)h) << 16);
}
static __device__ __forceinline__ void split2(float x, u16& h, u16& l) {
  u16 hb = f2bf(x); h = hb; l = f2bf(x - bf2f(hb));   // residual exact in fp32
}
static __device__ __forceinline__ void gl_lds16(const void* g, void* l) {
  __builtin_amdgcn_global_load_lds(
      (__attribute__((address_space(1))) void*)g,
      (__attribute__((address_space(3))) void*)l, 16, 0, 0);
}

// ---------------------------------------------------------------------------
// prep kernels: one-time fp32 -> bf16 split conversions
// ---------------------------------------------------------------------------
__global__ __launch_bounds__(256) void prep_split_kernel(
    const float* __restrict__ src, u16* __restrict__ dh, u16* __restrict__ dl,
    int n4)
{
  int i = blockIdx.x * 256 + threadIdx.x;
  if (i >= n4) return;
  float4 v = ((const float4*)src)[i];
  ushort4 h, l;
  split2(v.x, h.x, l.x); split2(v.y, h.y, l.y);
  split2(v.z, h.z, l.z); split2(v.w, h.w, l.w);
  ((ushort4*)dh)[i] = h; ((ushort4*)dl)[i] = l;
}

struct PrepArgs { const float* src[3]; u16* dh[3]; u16* dl[3]; };

__global__ __launch_bounds__(256) void prep_split3_kernel(PrepArgs a)
{
  const int m = blockIdx.y;
  int i = blockIdx.x * 256 + threadIdx.x;
  float4 v = ((const float4*)a.src[m])[i];
  ushort4 h, l;
  split2(v.x, h.x, l.x); split2(v.y, h.y, l.y);
  split2(v.z, h.z, l.z); split2(v.w, h.w, l.w);
  ((ushort4*)a.dh[m])[i] = h; ((ushort4*)a.dl[m])[i] = l;
}

__global__ __launch_bounds__(256) void prep_w_kernel(
    const float* __restrict__ Wq, const float* __restrict__ Wk,
    const float* __restrict__ Wv, const float* __restrict__ Wo,
    u16* __restrict__ wb)
{
  const int y = blockIdx.y;
  const float* src = (y == 0) ? Wq : (y == 1) ? Wk : (y == 2) ? Wv : Wo;
  int i = blockIdx.x * 256 + threadIdx.x;     // 65536 threads = WEL/4
  float4 v = ((const float4*)src)[i];
  if (y < 3) {
    ushort4 h, l;
    split2(v.x, h.x, l.x); split2(v.y, h.y, l.y);
    split2(v.z, h.z, l.z); split2(v.w, h.w, l.w);
    ((ushort4*)(wb + (size_t)y * 2 * WEL))[i] = h;
    ((ushort4*)(wb + (size_t)y * 2 * WEL + WEL))[i] = l;
  } else {
    ushort4 h;
    h.x = f2bf(v.x); h.y = f2bf(v.y); h.z = f2bf(v.z); h.w = f2bf(v.w);
    ((ushort4*)(wb + (size_t)6 * WEL))[i] = h;
  }
}

// ---------------------------------------------------------------------------
// proj: C = quantize(X@W^T + b), 3-pass split-bf16, 128x128 tile, BK=32
// ---------------------------------------------------------------------------
struct ProjArgs {
  const u16* Xh[3]; const u16* Xl[3];
  const u16* Wh[3]; const u16* Wl[3];
  const float* bias[3];
  u16* dst[3];
  int trans[3];
};

__global__ __launch_bounds__(256) void proj_kernel(ProjArgs args,
    const float* __restrict__ bparam, const float* __restrict__ eparam)
{
  __shared__ u16 sm[17408];                 // 34.8 KB (staging 32 KB + T-epilogue)
  u16* const Ah = sm;
  u16* const Al = sm + 4096;
  u16* const Bh = sm + 8192;
  u16* const Bl = sm + 12288;

  const int z = blockIdx.z;
  const u16* __restrict__ Xh = args.Xh[z];
  const u16* __restrict__ Xl = args.Xl[z];
  const u16* __restrict__ Wh = args.Wh[z];
  const u16* __restrict__ Wl = args.Wl[z];
  const float* __restrict__ bias = args.bias[z];
  u16* __restrict__ dst = args.dst[z];
  const int trans = args.trans[z];

  const int tid  = threadIdx.x;
  const int lane = tid & 63;
  const int wave = tid >> 6;
  const int lam  = lane & 31;
  const int hl   = lane >> 5;
  const int wm   = wave & 1;
  const int wn   = wave >> 1;
  const int mbase = blockIdx.x * 128;
  const int nbase = blockIdx.y * 128;

  const int srow = tid >> 2;
  const int skc  = ((tid & 3) - (tid >> 4)) & 3;
  const u16* gAh = Xh + (size_t)(mbase + srow) * 512 + skc * 8;
  const u16* gAl = Xl + (size_t)(mbase + srow) * 512 + skc * 8;
  const u16* gBh = Wh + (size_t)(nbase + srow) * 512 + skc * 8;
  const u16* gBl = Wl + (size_t)(nbase + srow) * 512 + skc * 8;
  const int lo = tid * 8;

  int offA[2][2], offB[2][2];
#pragma unroll
  for (int f = 0; f < 2; ++f)
#pragma unroll
    for (int kk = 0; kk < 2; ++kk) {
      int m = wm * 64 + f * 32 + lam;
      offA[f][kk] = m * 64 + (((2 * kk + hl) + (m >> 2)) & 3) * 16;
      int nn = wn * 64 + f * 32 + lam;
      offB[f][kk] = nn * 64 + (((2 * kk + hl) + (nn >> 2)) & 3) * 16;
    }

  f32x16 acc[2][2];
#pragma unroll
  for (int a = 0; a < 2; ++a)
#pragma unroll
    for (int b = 0; b < 2; ++b)
#pragma unroll
      for (int i = 0; i < 16; ++i) acc[a][b][i] = 0.f;

  for (int kt = 0; kt < 512; kt += 32) {
    __syncthreads();
    gl_lds16(gAh + kt,             Ah + lo);
    gl_lds16(gAh + kt + 64 * 512,  Ah + lo + 2048);
    gl_lds16(gAl + kt,             Al + lo);
    gl_lds16(gAl + kt + 64 * 512,  Al + lo + 2048);
    gl_lds16(gBh + kt,             Bh + lo);
    gl_lds16(gBh + kt + 64 * 512,  Bh + lo + 2048);
    gl_lds16(gBl + kt,             Bl + lo);
    gl_lds16(gBl + kt + 64 * 512,  Bl + lo + 2048);
    __syncthreads();

    bf16x8 fAh[2][2], fAl[2][2], fBh[2][2], fBl[2][2];
#pragma unroll
    for (int f = 0; f < 2; ++f)
#pragma unroll
      for (int kk = 0; kk < 2; ++kk) {
        fAh[f][kk] = *(const bf16x8*)((const char*)Ah + offA[f][kk]);
        fAl[f][kk] = *(const bf16x8*)((const char*)Al + offA[f][kk]);
        fBh[f][kk] = *(const bf16x8*)((const char*)Bh + offB[f][kk]);
        fBl[f][kk] = *(const bf16x8*)((const char*)Bl + offB[f][kk]);
      }
#pragma unroll
    for (int mf = 0; mf < 2; ++mf)
#pragma unroll
      for (int nf = 0; nf < 2; ++nf)
#pragma unroll
        for (int kk = 0; kk < 2; ++kk) {
          acc[mf][nf] = __builtin_amdgcn_mfma_f32_32x32x16_bf16(
              fAh[mf][kk], fBh[nf][kk], acc[mf][nf], 0, 0, 0);
          acc[mf][nf] = __builtin_amdgcn_mfma_f32_32x32x16_bf16(
              fAh[mf][kk], fBl[nf][kk], acc[mf][nf], 0, 0, 0);
          acc[mf][nf] = __builtin_amdgcn_mfma_f32_32x32x16_bf16(
              fAl[mf][kk], fBh[nf][kk], acc[mf][nf], 0, 0, 0);
        }
  }

  const float bq   = fminf(fmaxf(bparam[0], 1.0f), 8.0f);
  const float e    = eparam[0];
  const float s    = exp2f(e);
  const float invs = exp2f(-e);
  const float qlo  = -exp2f(bq - 1.0f);
  const float qhi  = exp2f(bq - 1.0f) - 1.0f;
  const int nidx = mbase >> 11;
  const int tb   = mbase & 2047;
  const int hb   = nbase >> 6;

  if (!trans) {
#pragma unroll
    for (int mf = 0; mf < 2; ++mf)
#pragma unroll
      for (int nf = 0; nf < 2; ++nf)
#pragma unroll
        for (int reg = 0; reg < 16; ++reg) {
          int col = wn * 64 + nf * 32 + lam;
          int row = wm * 64 + mf * 32 + (reg & 3) + 8 * (reg >> 2) + 4 * hl;
          float v = acc[mf][nf][reg] + bias[nbase + col];
          float qv = floorf(fminf(fmaxf(v * invs, qlo), qhi)) * s;
          dst[((size_t)(nidx * 8 + hb + (col >> 6)) * 2048 + tb + row) * 64 +
              (col & 63)] = f2bf(qv);
        }
  } else {
    __syncthreads();
#pragma unroll
    for (int mf = 0; mf < 2; ++mf)
#pragma unroll
      for (int nf = 0; nf < 2; ++nf)
#pragma unroll
        for (int reg = 0; reg < 16; ++reg) {
          int col = wn * 64 + nf * 32 + lam;
          int row = wm * 64 + mf * 32 + (reg & 3) + 8 * (reg >> 2) + 4 * hl;
          float v = acc[mf][nf][reg] + bias[nbase + col];
          float qv = floorf(fminf(fmaxf(v * invs, qlo), qhi)) * s;
          sm[col * 136 + row] = f2bf(qv);
        }
    __syncthreads();
    const int r = tid >> 1, half = tid & 1;
    const u16* sp = sm + r * 136 + half * 64;
    u16* gp = dst + ((size_t)(nidx * 8 + hb + (r >> 6)) * 64 + (r & 63)) * 2048 +
              tb + half * 64;
#pragma unroll
    for (int i = 0; i < 8; ++i)
      *(uint4*)(gp + i * 8) = *(const uint4*)(sp + i * 8);
  }
}

// ---------------------------------------------------------------------------
// attn: key-split waves. Block = 64 q-rows x all 2048 keys; per iteration
// 256 keys staged (64 per wave, wave-private region), each wave computes
// S^T + softmax + PV for all 64 q-rows against ITS keys. Cross-wave O/l
// reduction via LDS once at the end. LDS 70656 B -> 2 blocks/CU.
// ---------------------------------------------------------------------------
__global__ __launch_bounds__(256, 2) void attn_kernel(
    const u16* __restrict__ qbuf, const u16* __restrict__ kbuf,
    const u16* __restrict__ vtbuf, u16* __restrict__ ctx, int nbase)
{
  __shared__ u16 sm[35328];                 // K 32KB | V 32KB ; epilogue reuse
  char* const smc = (char*)sm;

  const int tid  = threadIdx.x;
  const int wave = tid >> 6;
  const int lane = tid & 63;
  const int lam  = lane & 31;
  const int hl   = lane >> 5;
  const int qt = blockIdx.x, hd = blockIdx.y;
  const int n  = blockIdx.z + nbase;
  const int nh = n * 8 + hd;
  const int qbase = qt * 64;

  const u16* Qp = qbuf + ((size_t)nh * 2048 + qbase) * 64;
  const u16* Kp = kbuf + (size_t)nh * 131072;
  const u16* Vp = vtbuf + (size_t)nh * 131072;

  bf16x8 qf[2][4];                          // B-operand: B[n=q][k=d]
#pragma unroll
  for (int qb = 0; qb < 2; ++qb)
#pragma unroll
    for (int dk = 0; dk < 4; ++dk)
      qf[qb][dk] = *(const bf16x8*)(Qp + (qb * 32 + lam) * 64 + dk * 16 + hl * 8);

  const float sc = (float)(1.4426950408889634 / 22.627416997969522); // log2e/sqrt(512)

  // staging: slot s in {tid, tid+256} per 64x64 tile; row=s>>3, chunk=(s&7)^(row&7)
  const int r0 = tid >> 3;
  const int j0 = (tid & 7) ^ (r0 & 7);
  const u16* gK0 = Kp + (size_t)r0 * 64 + j0 * 8;
  const u16* gK1 = Kp + (size_t)(r0 + 32) * 64 + j0 * 8;
  const u16* gV0 = Vp + (size_t)r0 * 2048 + j0 * 8;
  const u16* gV1 = Vp + (size_t)(r0 + 32) * 2048 + j0 * 8;

  // fragment byte offsets into the wave's private tile, swizzle c^(lam&7)
  int offK[2][4], offV[2][4];
#pragma unroll
  for (int kf = 0; kf < 2; ++kf)
#pragma unroll
    for (int dk = 0; dk < 4; ++dk)
      offK[kf][dk] = wave * 8192 + (kf * 32 + lam) * 128 +
                     (((2 * dk + hl) ^ (lam & 7)) * 16);
#pragma unroll
  for (int nf = 0; nf < 2; ++nf)
#pragma unroll
    for (int kk = 0; kk < 4; ++kk)
      offV[nf][kk] = 32768 + wave * 8192 + (nf * 32 + lam) * 128 +
                     (((2 * kk + hl) ^ (lam & 7)) * 16);

  float l_acc[2] = {0.f, 0.f};
  f32x16 O[2][2];
#pragma unroll
  for (int a = 0; a < 2; ++a)
#pragma unroll
    for (int b = 0; b < 2; ++b)
#pragma unroll
      for (int i = 0; i < 16; ++i) O[a][b][i] = 0.f;

  for (int kt = 0; kt < 2048; kt += 256) {
    __syncthreads();                        // prior tile's frag reads done
#pragma unroll
    for (int wt = 0; wt < 4; ++wt) {
      const size_t ko = (size_t)(kt + wt * 64) * 64;
      const int    vo = kt + wt * 64;
      gl_lds16(gK0 + ko, smc + wt * 8192 + tid * 16);
      gl_lds16(gK1 + ko, smc + wt * 8192 + tid * 16 + 4096);
      gl_lds16(gV0 + vo, smc + 32768 + wt * 8192 + tid * 16);
      gl_lds16(gV1 + vo, smc + 32768 + wt * 8192 + tid * 16 + 4096);
    }
    __syncthreads();                        // staging complete

#pragma unroll
    for (int kf = 0; kf < 2; ++kf) {
      bf16x8 Kf[4], Vf[2][2];
#pragma unroll
      for (int dk = 0; dk < 4; ++dk)
        Kf[dk] = *(const bf16x8*)(smc + offK[kf][dk]);
#pragma unroll
      for (int nf = 0; nf < 2; ++nf)
#pragma unroll
        for (int kkl = 0; kkl < 2; ++kkl)
          Vf[nf][kkl] = *(const bf16x8*)(smc + offV[nf][2 * kf + kkl]);

#pragma unroll
      for (int qb = 0; qb < 2; ++qb) {
        f32x16 S;
#pragma unroll
        for (int i = 0; i < 16; ++i) S[i] = 0.f;
#pragma unroll
        for (int dk = 0; dk < 4; ++dk)
          S = __builtin_amdgcn_mfma_f32_32x32x16_bf16(Kf[dk], qf[qb][dk],
                                                      S, 0, 0, 0);
        // no-max softmax; lane (lam,hl): q-row = qb*32+lam, key groups g&1==hl
        unsigned pk[4][2];
#pragma unroll
        for (int gh = 0; gh < 4; ++gh) {
          float p0 = __builtin_amdgcn_exp2f(S[4 * gh + 0] * sc);
          float p1 = __builtin_amdgcn_exp2f(S[4 * gh + 1] * sc);
          float p2 = __builtin_amdgcn_exp2f(S[4 * gh + 2] * sc);
          float p3 = __builtin_amdgcn_exp2f(S[4 * gh + 3] * sc);
          l_acc[qb] += (p0 + p1) + (p2 + p3);
          pk[gh][0] = __builtin_amdgcn_perm(__float_as_uint(p1),
                                            __float_as_uint(p0), 0x07060302u);
          pk[gh][1] = __builtin_amdgcn_perm(__float_as_uint(p3),
                                            __float_as_uint(p2), 0x07060302u);
        }
        // C->A transform: exchange complementary group with partner (^32)
        bf16x8 pfrag[2];
#pragma unroll
        for (int kkl = 0; kkl < 2; ++kkl) {
          unsigned s0 = hl ? pk[2 * kkl][0] : pk[2 * kkl + 1][0];
          unsigned s1 = hl ? pk[2 * kkl][1] : pk[2 * kkl + 1][1];
          unsigned o0 = hl ? pk[2 * kkl + 1][0] : pk[2 * kkl][0];
          unsigned o1 = hl ? pk[2 * kkl + 1][1] : pk[2 * kkl][1];
          unsigned rr0 = (unsigned)__shfl_xor((int)s0, 32);
          unsigned rr1 = (unsigned)__shfl_xor((int)s1, 32);
          u32x4 f;
          f[0] = hl ? rr0 : o0;
          f[1] = hl ? rr1 : o1;
          f[2] = hl ? o0 : rr0;
          f[3] = hl ? o1 : rr1;
          pfrag[kkl] = __builtin_bit_cast(bf16x8, f);
        }
#pragma unroll
        for (int nf = 0; nf < 2; ++nf)
#pragma unroll
          for (int kkl = 0; kkl < 2; ++kkl)
            O[qb][nf] = __builtin_amdgcn_mfma_f32_32x32x16_bf16(
                pfrag[kkl], Vf[nf][kkl], O[qb][nf], 0, 0, 0);
      }
    }
  }

  // ---- epilogue: cross-wave O/l reduction via LDS, normalize, store ----
#pragma unroll
  for (int qb = 0; qb < 2; ++qb) l_acc[qb] += __shfl_xor(l_acc[qb], 32);
  __syncthreads();                          // main-loop LDS reads done
  float* lred = (float*)(smc + 69632);      // [wave][q] 4x64 f32
  if (hl == 0) {
    lred[wave * 64 + lam]      = l_acc[0];
    lred[wave * 64 + 32 + lam] = l_acc[1];
  }
  float* Ow = (float*)(smc + wave * 17408); // [q][d] rows of 68 f32 (272 B)
#pragma unroll
  for (int qb = 0; qb < 2; ++qb)
#pragma unroll
    for (int nf = 0; nf < 2; ++nf)
#pragma unroll
      for (int r = 0; r < 16; ++r) {
        int qrow = qb * 32 + (r & 3) + 8 * (r >> 2) + 4 * hl;
        Ow[qrow * 68 + nf * 32 + lam] = O[qb][nf][r];
      }
  __syncthreads();

  const int q  = tid >> 2;                  // 0..63
  const int d4 = (tid & 3) * 64;            // byte offset of 16-f32 segment
  float acc[16];
  {
    const float4 v0 = *(const float4*)(smc + q * 272 + d4);
    const float4 v1 = *(const float4*)(smc + q * 272 + d4 + 16);
    const float4 v2 = *(const float4*)(smc + q * 272 + d4 + 32);
    const float4 v3 = *(const float4*)(smc + q * 272 + d4 + 48);
    acc[0]=v0.x; acc[1]=v0.y; acc[2]=v0.z; acc[3]=v0.w;
    acc[4]=v1.x; acc[5]=v1.y; acc[6]=v1.z; acc[7]=v1.w;
    acc[8]=v2.x; acc[9]=v2.y; acc[10]=v2.z; acc[11]=v2.w;
    acc[12]=v3.x; acc[13]=v3.y; acc[14]=v3.z; acc[15]=v3.w;
  }
#pragma unroll
  for (int w = 1; w < 4; ++w) {
    const char* b = smc + w * 17408 + q * 272 + d4;
    const float4 v0 = *(const float4*)(b);
    const float4 v1 = *(const float4*)(b + 16);
    const float4 v2 = *(const float4*)(b + 32);
    const float4 v3 = *(const float4*)(b + 48);
    acc[0]+=v0.x; acc[1]+=v0.y; acc[2]+=v0.z; acc[3]+=v0.w;
    acc[4]+=v1.x; acc[5]+=v1.y; acc[6]+=v1.z; acc[7]+=v1.w;
    acc[8]+=v2.x; acc[9]+=v2.y; acc[10]+=v2.z; acc[11]+=v2.w;
    acc[12]+=v3.x; acc[13]+=v3.y; acc[14]+=v3.z; acc[15]+=v3.w;
  }
  const float lsum = lred[q] + lred[64 + q] + lred[128 + q] + lred[192 + q];
  const float rinv = 1.0f / lsum;
  unsigned outp[8];
#pragma unroll
  for (int i = 0; i < 8; ++i) {
    float a0 = acc[2 * i] * rinv, a1 = acc[2 * i + 1] * rinv;
    outp[i] = (unsigned)f2bf(a0) | ((unsigned)f2bf(a1) << 16);
  }
  u16* cp = ctx + ((size_t)n * 2048 + qbase + q) * 512 + hd * 64 + (tid & 3) * 16;
  *(uint4*)cp       = *(const uint4*)&outp[0];
  *(uint4*)(cp + 8) = *(const uint4*)&outp[4];
}

// ---------------------------------------------------------------------------
// outproj: out = ctx @ Wo^T + bo  (single-pass bf16, fp32 out)
// ---------------------------------------------------------------------------
__global__ __launch_bounds__(256) void outproj_kernel(
    const u16* __restrict__ ctxb, const u16* __restrict__ Wob,
    const float* __restrict__ bias, float* __restrict__ out)
{
  __shared__ u16 sm[8192];
  u16* const As = sm;
  u16* const Bs = sm + 4096;

  const int tid  = threadIdx.x;
  const int lane = tid & 63;
  const int wave = tid >> 6;
  const int lam  = lane & 31;
  const int hl   = lane >> 5;
  const int wm   = wave & 1;
  const int wn   = wave >> 1;
  const int mbase = blockIdx.x * 128;
  const int nbase = blockIdx.y * 128;

  const int srow = tid >> 2;
  const int skc  = ((tid & 3) - (tid >> 4)) & 3;
  const u16* gA = ctxb + (size_t)(mbase + srow) * 512 + skc * 8;
  const u16* gB = Wob  + (size_t)(nbase + srow) * 512 + skc * 8;
  const int lo = tid * 8;

  int offA[2][2], offB[2][2];
#pragma unroll
  for (int f = 0; f < 2; ++f)
#pragma unroll
    for (int kk = 0; kk < 2; ++kk) {
      int m = wm * 64 + f * 32 + lam;
      offA[f][kk] = m * 64 + (((2 * kk + hl) + (m >> 2)) & 3) * 16;
      int nn = wn * 64 + f * 32 + lam;
      offB[f][kk] = nn * 64 + (((2 * kk + hl) + (nn >> 2)) & 3) * 16;
    }

  f32x16 acc[2][2];
#pragma unroll
  for (int a = 0; a < 2; ++a)
#pragma unroll
    for (int b = 0; b < 2; ++b)
#pragma unroll
      for (int i = 0; i < 16; ++i) acc[a][b][i] = 0.f;

  for (int kt = 0; kt < 512; kt += 32) {
    __syncthreads();
    gl_lds16(gA + kt,            As + lo);
    gl_lds16(gA + kt + 64 * 512, As + lo + 2048);
    gl_lds16(gB + kt,            Bs + lo);
    gl_lds16(gB + kt + 64 * 512, Bs + lo + 2048);
    __syncthreads();

    bf16x8 fA[2][2], fB[2][2];
#pragma unroll
    for (int f = 0; f < 2; ++f)
#pragma unroll
      for (int kk = 0; kk < 2; ++kk) {
        fA[f][kk] = *(const bf16x8*)((const char*)As + offA[f][kk]);
        fB[f][kk] = *(const bf16x8*)((const char*)Bs + offB[f][kk]);
      }
#pragma unroll
    for (int mf = 0; mf < 2; ++mf)
#pragma unroll
      for (int nf = 0; nf < 2; ++nf)
#pragma unroll
        for (int kk = 0; kk < 2; ++kk)
          acc[mf][nf] = __builtin_amdgcn_mfma_f32_32x32x16_bf16(
              fA[mf][kk], fB[nf][kk], acc[mf][nf], 0, 0, 0);
  }

#pragma unroll
  for (int mf = 0; mf < 2; ++mf)
#pragma unroll
    for (int nf = 0; nf < 2; ++nf)
#pragma unroll
      for (int reg = 0; reg < 16; ++reg) {
        int col = wn * 64 + nf * 32 + lam;
        int row = wm * 64 + mf * 32 + (reg & 3) + 8 * (reg >> 2) + 4 * hl;
        out[(size_t)(mbase + row) * 512 + nbase + col] =
            acc[mf][nf][reg] + bias[nbase + col];
      }
}

// ---------------------------------------------------------------------------
extern "C" void kernel_launch(void* const* d_in, const int* in_sizes, int n_in,
                              void* d_out, int out_size, void* d_ws, size_t ws_size,
                              hipStream_t stream) {
  (void)in_sizes; (void)n_in; (void)out_size;
  const float* values = (const float*)d_in[0];
  const float* keys   = (const float*)d_in[1];
  const float* query  = (const float*)d_in[2];
  const float* Wq = (const float*)d_in[3];  const float* bq = (const float*)d_in[4];
  const float* Wk = (const float*)d_in[5];  const float* bk = (const float*)d_in[6];
  const float* Wv = (const float*)d_in[7];  const float* bv = (const float*)d_in[8];
  const float* Wo = (const float*)d_in[9];  const float* bo = (const float*)d_in[10];
  const float* bp = (const float*)d_in[11]; const float* ep = (const float*)d_in[12];

  u16* ws    = (u16*)d_ws;
  u16* qbuf  = ws;
  u16* kbuf  = ws + (size_t)EL;
  u16* vtbuf = ws + (size_t)2 * EL;
  u16* wb    = ws + (size_t)3 * EL;            // 7*WEL of W splits
  u16* xb    = wb + (size_t)7 * WEL;           // X split region
  u16* ctx   = xb;                             // aliases Xh[0] (dead after proj)

  const float* Xsrc[3] = {query, keys, values};
  const float* Bsrc[3] = {bq, bk, bv};
  u16* Dst[3] = {qbuf, kbuf, vtbuf};

  prep_w_kernel<<<dim3(256, 4), 256, 0, stream>>>(Wq, Wk, Wv, Wo, wb);

  const bool par = ws_size >= (size_t)79167488;   // (9*EL + 7*WEL)*2 bytes
  if (par) {
    ProjArgs a;
    PrepArgs p;
    for (int m = 0; m < 3; ++m) {
      u16* xh = xb + (size_t)m * 2 * EL;
      p.src[m] = Xsrc[m]; p.dh[m] = xh; p.dl[m] = xh + EL;
      a.Xh[m] = xh; a.Xl[m] = xh + EL;
      a.Wh[m] = wb + (size_t)m * 2 * WEL; a.Wl[m] = wb + (size_t)m * 2 * WEL + WEL;
      a.bias[m] = Bsrc[m]; a.dst[m] = Dst[m]; a.trans[m] = (m == 2);
    }
    prep_split3_kernel<<<dim3(4096, 3), 256, 0, stream>>>(p);
    proj_kernel<<<dim3(64, 4, 3), 256, 0, stream>>>(a, bp, ep);
  } else {
    for (int m = 0; m < 3; ++m) {
      prep_split_kernel<<<4096, 256, 0, stream>>>(Xsrc[m], xb, xb + EL, EL / 4);
      ProjArgs a = {};
      a.Xh[0] = xb; a.Xl[0] = xb + EL;
      a.Wh[0] = wb + (size_t)m * 2 * WEL; a.Wl[0] = wb + (size_t)m * 2 * WEL + WEL;
      a.bias[0] = Bsrc[m]; a.dst[0] = Dst[m]; a.trans[0] = (m == 2);
      proj_kernel<<<dim3(64, 4, 1), 256, 0, stream>>>(a, bp, ep);
    }
  }

  // two half-batch dispatches: perf-neutral (512 blocks = 2/CU each, the LDS
  // cap), gives rocprof top-5 room to show proj/prep/outproj next round
  attn_kernel<<<dim3(32, 8, 2), 256, 0, stream>>>(qbuf, kbuf, vtbuf, ctx, 0);
  attn_kernel<<<dim3(32, 8, 2), 256, 0, stream>>>(qbuf, kbuf, vtbuf, ctx, 2);
  outproj_kernel<<<dim3(64, 4), 256, 0, stream>>>(ctx, wb + (size_t)6 * WEL, bo,
                                                  (float*)d_out);
}

// Round 7
// 192.912 us; speedup vs baseline: 1.7611x; 1.1827x over previous
//
#include <hip/hip_runtime.h>
#include <hip/hip_bf16.h>
#include <hip/hip_fp16.h>
#include <cstdint>
#include <cstddef>

// ---------------------------------------------------------------------------
// QuantizedMultiheadAttention  (N=4, T=2048, E=512, H=8, D=64)
//
// R7 = R6 with the cvt_pkrtz return-type fix (compile error only).
// Single-pass f16 pipeline:
//  f16's 11-bit mantissa gives q-error ~2e-4 (better than 2-pass split-bf16)
//  at 1/3 the MFMA work; quantized q/k/v are ints <=128 -> exact in f16;
//  P via v_cvt_pkrtz (2^-11, better than bf16 2^-8).
//
//  prep_all : 3 X + 4 W fp32 -> f16, one dispatch
//  proj     : q/k/v = quantize(X@W^T+b), 1-pass f16 MFMA 32x32x16, 128x128
//             tile, BK=64, global_load_lds(16B), 8-way XOR-swizzled LDS,
//             3 blocks/CU. v stored pre-transposed [N,H,D,T].
//  attn     : key-split waves (R5 structure), f16, single dispatch.
//  outproj  : out = ctx@Wo^T + bo, f16, 64x128 tiles (512 blocks).
// ---------------------------------------------------------------------------

typedef __attribute__((ext_vector_type(8))) _Float16 f16x8;
typedef __attribute__((ext_vector_type(2))) __fp16 hf16x2;   // cvt_pkrtz ret
typedef __attribute__((ext_vector_type(16))) float f32x16;
typedef __attribute__((ext_vector_type(4))) unsigned u32x4;
typedef unsigned short u16;

#define EL  4194304   // 4*2048*512 elements
#define WEL 262144    // 512*512

static __device__ __forceinline__ u16 f2h(float x) {
  _Float16 h = (_Float16)x;                      // v_cvt_f16_f32 (RNE)
  return __builtin_bit_cast(u16, h);
}
static __device__ __forceinline__ unsigned pkh2(float a, float b) {
  hf16x2 p = __builtin_amdgcn_cvt_pkrtz(a, b);   // packed f16, a=low b=high
  return __builtin_bit_cast(unsigned, p);
}
static __device__ __forceinline__ void gl_lds16(const void* g, void* l) {
  __builtin_amdgcn_global_load_lds(
      (__attribute__((address_space(1))) void*)g,
      (__attribute__((address_space(3))) void*)l, 16, 0, 0);
}

// ---------------------------------------------------------------------------
// prep_all: fp32 -> f16 for [query, keys, values, Wq, Wk, Wv, Wo] into one
// contiguous f16 region. Quad (float4) per thread; segments are multiples of
// 256 quads so the source pointer is block-uniform.
// ---------------------------------------------------------------------------
struct PrepAllArgs { const float* src[7]; };

__global__ __launch_bounds__(256) void prep_all_kernel(PrepAllArgs a,
                                                       u16* __restrict__ dst)
{
  const int i = blockIdx.x * 256 + threadIdx.x;   // quad index
  const float* src; int off;
  if (i < 3145728) {                              // 3 * EL/4, EL/4 = 2^20
    const int m = i >> 20; off = i & 1048575;
    src = (m == 0) ? a.src[0] : (m == 1) ? a.src[1] : a.src[2];
  } else {                                        // 4 * WEL/4, WEL/4 = 2^16
    const int j = i - 3145728; const int w = j >> 16; off = j & 65535;
    src = (w == 0) ? a.src[3] : (w == 1) ? a.src[4]
        : (w == 2) ? a.src[5] : a.src[6];
  }
  const float4 v = ((const float4*)src)[off];
  ushort4 o;
  o.x = f2h(v.x); o.y = f2h(v.y); o.z = f2h(v.z); o.w = f2h(v.w);
  ((ushort4*)dst)[i] = o;
}

// ---------------------------------------------------------------------------
// proj: C = quantize(X@W^T + b), single-pass f16, 128x128 tile, BK=64.
// LDS per 128x64 tile: row r (128B) holds chunk j at position j^(r&7)
// (full 8-way XOR swizzle; staging slots stay lane-ordered for DMA and
// frag ds_read_b128 is conflict-free).
// ---------------------------------------------------------------------------
struct ProjArgs {
  const u16* X[3]; const u16* W[3]; const float* bias[3];
  u16* dst[3]; int trans[3];
};

__global__ __launch_bounds__(256, 3) void proj_kernel(ProjArgs args,
    const float* __restrict__ bparam, const float* __restrict__ eparam)
{
  __shared__ u16 sm[17408];            // staging 32 KB; trans-epilogue 34816 B
  u16* const As = sm;                  // bytes [0, 16384)
  u16* const Bs = sm + 8192;           // bytes [16384, 32768)

  const int z = blockIdx.z;
  const u16* __restrict__ X = args.X[z];
  const u16* __restrict__ W = args.W[z];
  const float* __restrict__ bias = args.bias[z];
  u16* __restrict__ dst = args.dst[z];
  const int trans = args.trans[z];

  const int tid  = threadIdx.x;
  const int lane = tid & 63;
  const int wave = tid >> 6;
  const int lam  = lane & 31;
  const int hl   = lane >> 5;
  const int wm   = wave & 1;
  const int wn   = wave >> 1;
  const int mbase = blockIdx.x * 128;
  const int nbase = blockIdx.y * 128;

  // staging: slot s = tid + 256*t (t=0..3): row = s>>3, pos = tid&7,
  // source chunk j = (tid&7) ^ (row&7)  (row&7 invariant in t since 32t%8==0)
  const int srow = tid >> 3;                       // 0..31
  const int sj   = (tid & 7) ^ (srow & 7);
  const u16* gA = X + (size_t)(mbase + srow) * 512 + sj * 8;
  const u16* gB = W + (size_t)(nbase + srow) * 512 + sj * 8;

  // fragment byte offsets: chunk c = 2*kk+hl of row m at pos c^(m&7)
  int offA[2][4], offB[2][4];
#pragma unroll
  for (int f = 0; f < 2; ++f)
#pragma unroll
    for (int kk = 0; kk < 4; ++kk) {
      const int c = 2 * kk + hl;
      const int m = wm * 64 + f * 32 + lam;
      offA[f][kk] = m * 128 + ((c ^ (m & 7)) * 16);
      const int nn = wn * 64 + f * 32 + lam;
      offB[f][kk] = nn * 128 + ((c ^ (nn & 7)) * 16);
    }

  f32x16 acc[2][2];
#pragma unroll
  for (int a = 0; a < 2; ++a)
#pragma unroll
    for (int b = 0; b < 2; ++b)
#pragma unroll
      for (int i = 0; i < 16; ++i) acc[a][b][i] = 0.f;

  for (int kt = 0; kt < 512; kt += 64) {
    __syncthreads();                   // prior frag reads done
#pragma unroll
    for (int t = 0; t < 4; ++t) {
      gl_lds16(gA + kt + t * 32 * 512, (char*)As + tid * 16 + t * 4096);
      gl_lds16(gB + kt + t * 32 * 512, (char*)Bs + tid * 16 + t * 4096);
    }
    __syncthreads();                   // staging complete

    f16x8 fA[2][4], fB[2][4];
#pragma unroll
    for (int f = 0; f < 2; ++f)
#pragma unroll
      for (int kk = 0; kk < 4; ++kk) {
        fA[f][kk] = *(const f16x8*)((const char*)As + offA[f][kk]);
        fB[f][kk] = *(const f16x8*)((const char*)Bs + offB[f][kk]);
      }
#pragma unroll
    for (int mf = 0; mf < 2; ++mf)
#pragma unroll
      for (int nf = 0; nf < 2; ++nf)
#pragma unroll
        for (int kk = 0; kk < 4; ++kk)
          acc[mf][nf] = __builtin_amdgcn_mfma_f32_32x32x16_f16(
              fA[mf][kk], fB[nf][kk], acc[mf][nf], 0, 0, 0);
  }

  // quantize epilogue: floor(clip(v/2^e, -2^(b-1), 2^(b-1)-1)) * 2^e
  const float bq   = fminf(fmaxf(bparam[0], 1.0f), 8.0f);
  const float e    = eparam[0];
  const float s    = exp2f(e);
  const float invs = exp2f(-e);
  const float qlo  = -exp2f(bq - 1.0f);
  const float qhi  = exp2f(bq - 1.0f) - 1.0f;
  const int nidx = mbase >> 11;        // batch
  const int tb   = mbase & 2047;       // t base
  const int hb   = nbase >> 6;         // head base (2 heads per col-tile)

  if (!trans) {
#pragma unroll
    for (int mf = 0; mf < 2; ++mf)
#pragma unroll
      for (int nf = 0; nf < 2; ++nf)
#pragma unroll
        for (int reg = 0; reg < 16; ++reg) {
          int col = wn * 64 + nf * 32 + lam;
          int row = wm * 64 + mf * 32 + (reg & 3) + 8 * (reg >> 2) + 4 * hl;
          float v = acc[mf][nf][reg] + bias[nbase + col];
          float qv = floorf(fminf(fmaxf(v * invs, qlo), qhi)) * s;
          dst[((size_t)(nidx * 8 + hb + (col >> 6)) * 2048 + tb + row) * 64 +
              (col & 63)] = f2h(qv);
        }
  } else {
    __syncthreads();                   // staging LDS reads done everywhere
#pragma unroll
    for (int mf = 0; mf < 2; ++mf)
#pragma unroll
      for (int nf = 0; nf < 2; ++nf)
#pragma unroll
        for (int reg = 0; reg < 16; ++reg) {
          int col = wn * 64 + nf * 32 + lam;
          int row = wm * 64 + mf * 32 + (reg & 3) + 8 * (reg >> 2) + 4 * hl;
          float v = acc[mf][nf][reg] + bias[nbase + col];
          float qv = floorf(fminf(fmaxf(v * invs, qlo), qhi)) * s;
          sm[col * 136 + row] = f2h(qv);   // [d col][t row], stride 136
        }
    __syncthreads();
    const int r = tid >> 1, half = tid & 1;
    const u16* sp = sm + r * 136 + half * 64;
    u16* gp = dst + ((size_t)(nidx * 8 + hb + (r >> 6)) * 64 + (r & 63)) * 2048 +
              tb + half * 64;
#pragma unroll
    for (int i = 0; i < 8; ++i)
      *(uint4*)(gp + i * 8) = *(const uint4*)(sp + i * 8);
  }
}

// ---------------------------------------------------------------------------
// attn: key-split waves (R5 structure), f16. Block = 64 q-rows x 2048 keys;
// per iter 256 keys staged (64 per wave, wave-private), cross-wave O/l
// reduction once at end. S^T no-max softmax; P C->A via __shfl_xor(32).
// ---------------------------------------------------------------------------
__global__ __launch_bounds__(256, 2) void attn_kernel(
    const u16* __restrict__ qbuf, const u16* __restrict__ kbuf,
    const u16* __restrict__ vtbuf, u16* __restrict__ ctx)
{
  __shared__ u16 sm[35328];            // K 32KB | V 32KB ; epilogue reuse
  char* const smc = (char*)sm;

  const int tid  = threadIdx.x;
  const int wave = tid >> 6;
  const int lane = tid & 63;
  const int lam  = lane & 31;
  const int hl   = lane >> 5;
  const int qt = blockIdx.x, hd = blockIdx.y, n = blockIdx.z;
  const int nh = n * 8 + hd;
  const int qbase = qt * 64;

  const u16* Qp = qbuf + ((size_t)nh * 2048 + qbase) * 64;
  const u16* Kp = kbuf + (size_t)nh * 131072;
  const u16* Vp = vtbuf + (size_t)nh * 131072;

  f16x8 qf[2][4];                      // B-operand: B[n=q][k=d]
#pragma unroll
  for (int qb = 0; qb < 2; ++qb)
#pragma unroll
    for (int dk = 0; dk < 4; ++dk)
      qf[qb][dk] = *(const f16x8*)(Qp + (qb * 32 + lam) * 64 + dk * 16 + hl * 8);

  const float sc = (float)(1.4426950408889634 / 22.627416997969522); // log2e/sqrt(512)

  const int r0 = tid >> 3;
  const int j0 = (tid & 7) ^ (r0 & 7);
  const u16* gK0 = Kp + (size_t)r0 * 64 + j0 * 8;
  const u16* gK1 = Kp + (size_t)(r0 + 32) * 64 + j0 * 8;
  const u16* gV0 = Vp + (size_t)r0 * 2048 + j0 * 8;
  const u16* gV1 = Vp + (size_t)(r0 + 32) * 2048 + j0 * 8;

  int offK[2][4], offV[2][4];
#pragma unroll
  for (int kf = 0; kf < 2; ++kf)
#pragma unroll
    for (int dk = 0; dk < 4; ++dk)
      offK[kf][dk] = wave * 8192 + (kf * 32 + lam) * 128 +
                     (((2 * dk + hl) ^ (lam & 7)) * 16);
#pragma unroll
  for (int nf = 0; nf < 2; ++nf)
#pragma unroll
    for (int kk = 0; kk < 4; ++kk)
      offV[nf][kk] = 32768 + wave * 8192 + (nf * 32 + lam) * 128 +
                     (((2 * kk + hl) ^ (lam & 7)) * 16);

  float l_acc[2] = {0.f, 0.f};
  f32x16 O[2][2];
#pragma unroll
  for (int a = 0; a < 2; ++a)
#pragma unroll
    for (int b = 0; b < 2; ++b)
#pragma unroll
      for (int i = 0; i < 16; ++i) O[a][b][i] = 0.f;

  for (int kt = 0; kt < 2048; kt += 256) {
    __syncthreads();
#pragma unroll
    for (int wt = 0; wt < 4; ++wt) {
      const size_t ko = (size_t)(kt + wt * 64) * 64;
      const int    vo = kt + wt * 64;
      gl_lds16(gK0 + ko, smc + wt * 8192 + tid * 16);
      gl_lds16(gK1 + ko, smc + wt * 8192 + tid * 16 + 4096);
      gl_lds16(gV0 + vo, smc + 32768 + wt * 8192 + tid * 16);
      gl_lds16(gV1 + vo, smc + 32768 + wt * 8192 + tid * 16 + 4096);
    }
    __syncthreads();

#pragma unroll
    for (int kf = 0; kf < 2; ++kf) {
      f16x8 Kf[4], Vf[2][2];
#pragma unroll
      for (int dk = 0; dk < 4; ++dk)
        Kf[dk] = *(const f16x8*)(smc + offK[kf][dk]);
#pragma unroll
      for (int nf = 0; nf < 2; ++nf)
#pragma unroll
        for (int kkl = 0; kkl < 2; ++kkl)
          Vf[nf][kkl] = *(const f16x8*)(smc + offV[nf][2 * kf + kkl]);

#pragma unroll
      for (int qb = 0; qb < 2; ++qb) {
        f32x16 S;
#pragma unroll
        for (int i = 0; i < 16; ++i) S[i] = 0.f;
#pragma unroll
        for (int dk = 0; dk < 4; ++dk)
          S = __builtin_amdgcn_mfma_f32_32x32x16_f16(Kf[dk], qf[qb][dk],
                                                     S, 0, 0, 0);
        // no-max softmax; lane (lam,hl): q-row qb*32+lam, key groups g&1==hl
        unsigned pk[4][2];
#pragma unroll
        for (int gh = 0; gh < 4; ++gh) {
          float p0 = __builtin_amdgcn_exp2f(S[4 * gh + 0] * sc);
          float p1 = __builtin_amdgcn_exp2f(S[4 * gh + 1] * sc);
          float p2 = __builtin_amdgcn_exp2f(S[4 * gh + 2] * sc);
          float p3 = __builtin_amdgcn_exp2f(S[4 * gh + 3] * sc);
          l_acc[qb] += (p0 + p1) + (p2 + p3);
          pk[gh][0] = pkh2(p0, p1);
          pk[gh][1] = pkh2(p2, p3);
        }
        // C->A transform: exchange complementary group with partner (^32)
        f16x8 pfrag[2];
#pragma unroll
        for (int kkl = 0; kkl < 2; ++kkl) {
          unsigned s0 = hl ? pk[2 * kkl][0] : pk[2 * kkl + 1][0];
          unsigned s1 = hl ? pk[2 * kkl][1] : pk[2 * kkl + 1][1];
          unsigned o0 = hl ? pk[2 * kkl + 1][0] : pk[2 * kkl][0];
          unsigned o1 = hl ? pk[2 * kkl + 1][1] : pk[2 * kkl][1];
          unsigned rr0 = (unsigned)__shfl_xor((int)s0, 32);
          unsigned rr1 = (unsigned)__shfl_xor((int)s1, 32);
          u32x4 f;
          f[0] = hl ? rr0 : o0;
          f[1] = hl ? rr1 : o1;
          f[2] = hl ? o0 : rr0;
          f[3] = hl ? o1 : rr1;
          pfrag[kkl] = __builtin_bit_cast(f16x8, f);
        }
#pragma unroll
        for (int nf = 0; nf < 2; ++nf)
#pragma unroll
          for (int kkl = 0; kkl < 2; ++kkl)
            O[qb][nf] = __builtin_amdgcn_mfma_f32_32x32x16_f16(
                pfrag[kkl], Vf[nf][kkl], O[qb][nf], 0, 0, 0);
      }
    }
  }

  // ---- epilogue: cross-wave O/l reduction via LDS, normalize, store ----
#pragma unroll
  for (int qb = 0; qb < 2; ++qb) l_acc[qb] += __shfl_xor(l_acc[qb], 32);
  __syncthreads();
  float* lred = (float*)(smc + 69632);
  if (hl == 0) {
    lred[wave * 64 + lam]      = l_acc[0];
    lred[wave * 64 + 32 + lam] = l_acc[1];
  }
  float* Ow = (float*)(smc + wave * 17408);   // [q][d] rows of 68 f32
#pragma unroll
  for (int qb = 0; qb < 2; ++qb)
#pragma unroll
    for (int nf = 0; nf < 2; ++nf)
#pragma unroll
      for (int r = 0; r < 16; ++r) {
        int qrow = qb * 32 + (r & 3) + 8 * (r >> 2) + 4 * hl;
        Ow[qrow * 68 + nf * 32 + lam] = O[qb][nf][r];
      }
  __syncthreads();

  const int q  = tid >> 2;
  const int d4 = (tid & 3) * 64;
  float acc[16];
  {
    const float4 v0 = *(const float4*)(smc + q * 272 + d4);
    const float4 v1 = *(const float4*)(smc + q * 272 + d4 + 16);
    const float4 v2 = *(const float4*)(smc + q * 272 + d4 + 32);
    const float4 v3 = *(const float4*)(smc + q * 272 + d4 + 48);
    acc[0]=v0.x; acc[1]=v0.y; acc[2]=v0.z; acc[3]=v0.w;
    acc[4]=v1.x; acc[5]=v1.y; acc[6]=v1.z; acc[7]=v1.w;
    acc[8]=v2.x; acc[9]=v2.y; acc[10]=v2.z; acc[11]=v2.w;
    acc[12]=v3.x; acc[13]=v3.y; acc[14]=v3.z; acc[15]=v3.w;
  }
#pragma unroll
  for (int w = 1; w < 4; ++w) {
    const char* b = smc + w * 17408 + q * 272 + d4;
    const float4 v0 = *(const float4*)(b);
    const float4 v1 = *(const float4*)(b + 16);
    const float4 v2 = *(const float4*)(b + 32);
    const float4 v3 = *(const float4*)(b + 48);
    acc[0]+=v0.x; acc[1]+=v0.y; acc[2]+=v0.z; acc[3]+=v0.w;
    acc[4]+=v1.x; acc[5]+=v1.y; acc[6]+=v1.z; acc[7]+=v1.w;
    acc[8]+=v2.x; acc[9]+=v2.y; acc[10]+=v2.z; acc[11]+=v2.w;
    acc[12]+=v3.x; acc[13]+=v3.y; acc[14]+=v3.z; acc[15]+=v3.w;
  }
  const float lsum = lred[q] + lred[64 + q] + lred[128 + q] + lred[192 + q];
  const float rinv = 1.0f / lsum;
  unsigned outp[8];
#pragma unroll
  for (int i = 0; i < 8; ++i)
    outp[i] = pkh2(acc[2 * i] * rinv, acc[2 * i + 1] * rinv);
  u16* cp = ctx + ((size_t)n * 2048 + qbase + q) * 512 + hd * 64 + (tid & 3) * 16;
  *(uint4*)cp       = *(const uint4*)&outp[0];
  *(uint4*)(cp + 8) = *(const uint4*)&outp[4];
}

// ---------------------------------------------------------------------------
// outproj: out = ctx @ Wo^T + bo, f16, 64x128 tile, BK=64 (512 blocks)
// ---------------------------------------------------------------------------
__global__ __launch_bounds__(256) void outproj_kernel(
    const u16* __restrict__ ctxb, const u16* __restrict__ Wof,
    const float* __restrict__ bias, float* __restrict__ out)
{
  __shared__ u16 sm[12288];            // A 8KB | B 16KB
  u16* const As = sm;                  // bytes [0, 8192)
  u16* const Bs = sm + 4096;           // bytes [8192, 24576)

  const int tid  = threadIdx.x;
  const int lane = tid & 63;
  const int wave = tid >> 6;
  const int lam  = lane & 31;
  const int hl   = lane >> 5;
  const int wm   = wave & 1;
  const int wn   = wave >> 1;
  const int mbase = blockIdx.x * 64;
  const int nbase = blockIdx.y * 128;

  const int srow = tid >> 3;
  const int sj   = (tid & 7) ^ (srow & 7);
  const u16* gA = ctxb + (size_t)(mbase + srow) * 512 + sj * 8;
  const u16* gB = Wof  + (size_t)(nbase + srow) * 512 + sj * 8;

  int offA[4], offB[2][4];
#pragma unroll
  for (int kk = 0; kk < 4; ++kk) {
    const int c = 2 * kk + hl;
    const int m = wm * 32 + lam;
    offA[kk] = m * 128 + ((c ^ (m & 7)) * 16);
#pragma unroll
    for (int f = 0; f < 2; ++f) {
      const int nn = wn * 64 + f * 32 + lam;
      offB[f][kk] = nn * 128 + ((c ^ (nn & 7)) * 16);
    }
  }

  f32x16 acc[2];
#pragma unroll
  for (int a = 0; a < 2; ++a)
#pragma unroll
    for (int i = 0; i < 16; ++i) acc[a][i] = 0.f;

  for (int kt = 0; kt < 512; kt += 64) {
    __syncthreads();
#pragma unroll
    for (int t = 0; t < 2; ++t)
      gl_lds16(gA + kt + t * 32 * 512, (char*)As + tid * 16 + t * 4096);
#pragma unroll
    for (int t = 0; t < 4; ++t)
      gl_lds16(gB + kt + t * 32 * 512, (char*)Bs + tid * 16 + t * 4096);
    __syncthreads();

    f16x8 fA[4], fB[2][4];
#pragma unroll
    for (int kk = 0; kk < 4; ++kk) {
      fA[kk] = *(const f16x8*)((const char*)As + offA[kk]);
#pragma unroll
      for (int f = 0; f < 2; ++f)
        fB[f][kk] = *(const f16x8*)((const char*)Bs + offB[f][kk]);
    }
#pragma unroll
    for (int nf = 0; nf < 2; ++nf)
#pragma unroll
      for (int kk = 0; kk < 4; ++kk)
        acc[nf] = __builtin_amdgcn_mfma_f32_32x32x16_f16(
            fA[kk], fB[nf][kk], acc[nf], 0, 0, 0);
  }

#pragma unroll
  for (int nf = 0; nf < 2; ++nf)
#pragma unroll
    for (int reg = 0; reg < 16; ++reg) {
      int col = nbase + wn * 64 + nf * 32 + lam;
      int row = mbase + wm * 32 + (reg & 3) + 8 * (reg >> 2) + 4 * hl;
      out[(size_t)row * 512 + col] = acc[nf][reg] + bias[col];
    }
}

// ---------------------------------------------------------------------------
extern "C" void kernel_launch(void* const* d_in, const int* in_sizes, int n_in,
                              void* d_out, int out_size, void* d_ws, size_t ws_size,
                              hipStream_t stream) {
  (void)in_sizes; (void)n_in; (void)out_size; (void)ws_size;
  const float* values = (const float*)d_in[0];
  const float* keys   = (const float*)d_in[1];
  const float* query  = (const float*)d_in[2];
  const float* Wq = (const float*)d_in[3];  const float* bq = (const float*)d_in[4];
  const float* Wk = (const float*)d_in[5];  const float* bk = (const float*)d_in[6];
  const float* Wv = (const float*)d_in[7];  const float* bv = (const float*)d_in[8];
  const float* Wo = (const float*)d_in[9];  const float* bo = (const float*)d_in[10];
  const float* bp = (const float*)d_in[11]; const float* ep = (const float*)d_in[12];

  // ws layout (u16): qbuf EL | kbuf EL | vtbuf EL | ctx EL |
  //                  xwf = [xq EL, xk EL, xv EL, Wq..Wo WEL each]
  u16* ws    = (u16*)d_ws;
  u16* qbuf  = ws;
  u16* kbuf  = ws + (size_t)EL;
  u16* vtbuf = ws + (size_t)2 * EL;
  u16* ctx   = ws + (size_t)3 * EL;
  u16* xwf   = ws + (size_t)4 * EL;

  PrepAllArgs pa;
  pa.src[0] = query; pa.src[1] = keys; pa.src[2] = values;
  pa.src[3] = Wq; pa.src[4] = Wk; pa.src[5] = Wv; pa.src[6] = Wo;
  prep_all_kernel<<<13312, 256, 0, stream>>>(pa, xwf);

  const float* Bsrc[3] = {bq, bk, bv};
  u16* Dst[3] = {qbuf, kbuf, vtbuf};
  ProjArgs a;
  for (int m = 0; m < 3; ++m) {
    a.X[m] = xwf + (size_t)m * EL;
    a.W[m] = xwf + (size_t)3 * EL + (size_t)m * WEL;
    a.bias[m] = Bsrc[m]; a.dst[m] = Dst[m]; a.trans[m] = (m == 2);
  }
  proj_kernel<<<dim3(64, 4, 3), 256, 0, stream>>>(a, bp, ep);

  attn_kernel<<<dim3(32, 8, 4), 256, 0, stream>>>(qbuf, kbuf, vtbuf, ctx);
  outproj_kernel<<<dim3(128, 4), 256, 0, stream>>>(
      ctx, xwf + (size_t)3 * EL + (size_t)3 * WEL, bo, (float*)d_out);
}